// Round 7
// baseline (1111.457 us; speedup 1.0000x reference)
//
#include <hip/hip_runtime.h>
#include <hip/hip_bf16.h>
#include <math.h>

#define NN 3
#define BB 4
#define CC 256
#define C2 512
#define HH 40
#define WW 40
#define PP 1600
#define NBB 12                  // NN*BB
#define NODESZ (NBB*CC*PP)      // 4,915,200
#define TO 16                   // theta: output channels per block
#define PAD 1764                // 42*42 padded pixels

typedef short short8 __attribute__((ext_vector_type(8)));
typedef float f32x4 __attribute__((ext_vector_type(4)));
typedef unsigned short ushort_t;
typedef unsigned int uint_t;

__device__ __forceinline__ ushort_t f2bf(float x) {
  union { float f; uint_t u; } v; v.f = x;
  uint_t r = v.u + 0x7fff + ((v.u >> 16) & 1);
  return (ushort_t)(r >> 16);
}

__device__ __forceinline__ void async_ld16(const ushort_t* g, ushort_t* l) {
  __builtin_amdgcn_global_load_lds(
      (const __attribute__((address_space(1))) uint_t*)g,
      (__attribute__((address_space(3))) uint_t*)l, 16, 0, 0);
}

__global__ void k_copy(const float* __restrict__ in, float* __restrict__ out) {
  int i = blockIdx.x * 256 + threadIdx.x;
  out[i] = in[i];
}

// th_t[nb][p][c] (bf16) = tb[o] + sum_c tw[o,c] * nodes[nb,c,p]
__global__ void k_theta(const float* __restrict__ nodes, const float* __restrict__ tw,
                        const float* __restrict__ tb, ushort_t* __restrict__ th_t) {
  __shared__ float w[TO * CC];
  int t = threadIdx.x;
  int nb = blockIdx.y / (CC / TO);
  int o0 = (blockIdx.y % (CC / TO)) * TO;
  for (int i = t; i < TO * CC; i += 320) w[i] = tw[(o0 + (i >> 8)) * CC + (i & 255)];
  __syncthreads();
  int p = blockIdx.x * 320 + t;
  const float* src = nodes + nb * CC * PP + p;
  float acc[TO];
#pragma unroll
  for (int o = 0; o < TO; ++o) acc[o] = tb[o0 + o];
  for (int c = 0; c < CC; c += 4) {
    float v0 = src[c * PP], v1 = src[(c + 1) * PP], v2 = src[(c + 2) * PP], v3 = src[(c + 3) * PP];
#pragma unroll
    for (int o = 0; o < TO; ++o) {
      const float4 ww = *(const float4*)(w + o * CC + c);
      acc[o] += ww.x * v0 + ww.y * v1 + ww.z * v2 + ww.w * v3;
    }
  }
  size_t base = ((size_t)nb * PP + p) * CC + o0;
#pragma unroll
  for (int o = 0; o < TO; o += 2) {
    uint_t lo = f2bf(acc[o]), hi = f2bf(acc[o + 1]);
    *(uint_t*)&th_t[base + o] = lo | (hi << 16);
  }
}

// nodes [12][256][1600] fp32 -> nodes_bf_t [12][1600][256] bf16 (transpose),
// with 16B-chunk XOR swizzle within each row: c' = c ^ ((q&7)<<3).
// (Consumed only by k_attn_mfma, which un-XORs on its LDS frag reads.)
__global__ void k_to_bf_t(const float* __restrict__ src, ushort_t* __restrict__ dst) {
  __shared__ float tile[32][33];
  int nb = blockIdx.z;
  int c0 = blockIdx.y * 32;
  int pp0 = blockIdx.x * 32;
  int tx = threadIdx.x & 31, ty = threadIdx.x >> 5;
#pragma unroll
  for (int i = 0; i < 4; ++i)
    tile[ty + 8 * i][tx] = src[((size_t)nb * CC + c0 + ty + 8 * i) * PP + pp0 + tx];
  __syncthreads();
#pragma unroll
  for (int i = 0; i < 4; ++i) {
    int q = pp0 + ty + 8 * i;
    int c = c0 + tx;
    int cs = c ^ ((q & 7) << 3);
    dst[((size_t)nb * PP + q) * CC + cs] = f2bf(tile[tx][ty + 8 * i]);
  }
}

// vf frag-major bf16: vf[eb][T][nt][lane(quad,l16)][j]
//   = nodes[recv][c][p] + nodes[send][c][p],  c = 16nt + l16, p = 32T + quad*8 + j
// Each (T,nt) PV B-fragment = contiguous 1KB, one coalesced load in attn.
__global__ void k_prep_vf(const float* __restrict__ nodes, ushort_t* __restrict__ vf) {
  int T = blockIdx.x;                   // 0..49
  int eb = blockIdx.y;                  // 0..23
  int e = eb >> 2, b = eb & 3;
  int n = e >> 1, jidx = e & 1;
  int js = jidx + (jidx >= n ? 1 : 0);
  const float* s0 = nodes + (size_t)(n * BB + b) * CC * PP;
  const float* s1 = nodes + (size_t)(js * BB + b) * CC * PP;
  ushort_t* dst = vf + ((size_t)eb * 50 + T) * 8192;
  int t = threadIdx.x;
#pragma unroll
  for (int k = 0; k < 4; ++k) {
    int cid = t + 256 * k;              // 0..1023 (16 nt x 64 lanes)
    int nt = cid >> 6, l = cid & 63;
    int quad = l >> 4, l16 = l & 15;
    int c = 16 * nt + l16;
    int p = 32 * T + quad * 8;
    const float4* a0 = (const float4*)(s0 + (size_t)c * PP + p);
    const float4* a1 = (const float4*)(s1 + (size_t)c * PP + p);
    float4 x0 = a0[0], x1 = a0[1];
    float4 y0 = a1[0], y1 = a1[1];
    short8 o;
    o[0] = (short)f2bf(x0.x + y0.x); o[1] = (short)f2bf(x0.y + y0.y);
    o[2] = (short)f2bf(x0.z + y0.z); o[3] = (short)f2bf(x0.w + y0.w);
    o[4] = (short)f2bf(x1.x + y1.x); o[5] = (short)f2bf(x1.y + y1.y);
    o[6] = (short)f2bf(x1.z + y1.z); o[7] = (short)f2bf(x1.w + y1.w);
    *(short8*)(dst + (size_t)cid * 8) = o;
  }
}

// Flash attention, 64-p block, 4 waves, swapped-S softmax.  (unchanged from R6:
// L2/L3-BW-bound at ~1.04 GB/dispatch; dropped out of the profile top-5.)
__global__ __launch_bounds__(256, 2) void k_attn_mfma(
    const ushort_t* __restrict__ nodes_bf_t,  // [12][1600][256] chunk-swizzled
    const ushort_t* __restrict__ th_t,        // [12][1600][256] plain
    const ushort_t* __restrict__ vf,          // [24][50][16][512] frag-major
    float* __restrict__ agg_t)                // [2][12][1600][256]
{
  __shared__ ushort_t Ej[32 * 256];   // 16 KB
  __shared__ ushort_t Sp[64 * 40];    // 5 KB (rows padded to 40 u16 = 80B)
  __shared__ float Al[64];
  __shared__ float Linv[64];

  const int t = threadIdx.x;
  const int w = t >> 6;               // 0..3
  const int l = t & 63;
  const int quad = l >> 4;
  const int l16 = l & 15;
  const int p0 = blockIdx.x * 64;
  const int nb = blockIdx.y;
  const int jidx = blockIdx.z;
  const int n = nb >> 2, b = nb & 3;
  const int e = n * 2 + jidx;
  const int js = jidx + (jidx >= n ? 1 : 0);
  const int eb = e * BB + b;

  const ushort_t* ejb = nodes_bf_t + ((size_t)(js * BB + b) * PP) * CC;  // [q][c-swz]
  const ushort_t* vbase = vf + (size_t)eb * 50 * 8192;

  // th B-frags for this wave's rows p = p0 + 16w + l16 (resident all iters)
  short8 Ath[8];
  {
    const ushort_t* arow = th_t + ((size_t)nb * PP + p0 + 16 * w + l16) * CC + quad * 8;
#pragma unroll
    for (int ks = 0; ks < 8; ++ks) Ath[ks] = *(const short8*)(arow + ks * 32);
  }

  float M = -3.0e38f, Lr = 0.f;       // per-lane: this lane's p-row state
  f32x4 O[4][4];
#pragma unroll
  for (int mt = 0; mt < 4; ++mt)
#pragma unroll
    for (int nt = 0; nt < 4; ++nt)
#pragma unroll
      for (int r = 0; r < 4; ++r) O[mt][nt][r] = 0.f;

  // prologue: stage q-tile 0 (16 chunks of 1KB, wave w does 4)
#pragma unroll
  for (int i = 0; i < 4; ++i)
    async_ld16(ejb + (4 * w + i) * 512 + l * 8, &Ej[(4 * w + i) * 512]);

  for (int T = 0; T < 50; ++T) {
    __syncthreads();   // A: Ej[T] landed (barrier drains vmcnt); Sp/Al free
    // V frags for this iter (coalesced 1KB each); vmcnt-covered by S+softmax
    short8 Bv[4];
    {
      const ushort_t* vt = vbase + (size_t)T * 8192;
#pragma unroll
      for (int nt = 0; nt < 4; ++nt)
        Bv[nt] = *(const short8*)(vt + (4 * w + nt) * 512 + l * 8);
    }
    // ---- swapped S-GEMM: S^T[q][p], rows q = quad*4+r (+16), cols p = l16 ----
    f32x4 S0, S1;
#pragma unroll
    for (int r = 0; r < 4; ++r) { S0[r] = 0.f; S1[r] = 0.f; }
#pragma unroll
    for (int ks = 0; ks < 8; ++ks) {
      int ch0 = (((ks * 4 + quad) ^ (l16 & 7)) << 3);
      short8 A0 = *(const short8*)(Ej + l16 * CC + ch0);
      short8 A1 = *(const short8*)(Ej + (16 + l16) * CC + ch0);
      S0 = __builtin_amdgcn_mfma_f32_16x16x32_bf16(A0, Ath[ks], S0, 0, 0, 0);
      S1 = __builtin_amdgcn_mfma_f32_16x16x32_bf16(A1, Ath[ks], S1, 0, 0, 0);
    }
    // ---- softmax: 8 in-lane q-values for p = p0+16w+l16; reduce across quads ----
    float m = fmaxf(fmaxf(fmaxf(S0[0], S0[1]), fmaxf(S0[2], S0[3])),
                    fmaxf(fmaxf(S1[0], S1[1]), fmaxf(S1[2], S1[3])));
    m = fmaxf(m, __shfl_xor(m, 16));
    m = fmaxf(m, __shfl_xor(m, 32));
    float Mn = fmaxf(M, m);
    float al = __expf(M - Mn);
    float e0 = __expf(S0[0] - Mn), e1 = __expf(S0[1] - Mn);
    float e2 = __expf(S0[2] - Mn), e3 = __expf(S0[3] - Mn);
    float e4 = __expf(S1[0] - Mn), e5 = __expf(S1[1] - Mn);
    float e6 = __expf(S1[2] - Mn), e7 = __expf(S1[3] - Mn);
    float s = ((e0 + e1) + (e2 + e3)) + ((e4 + e5) + (e6 + e7));
    s += __shfl_xor(s, 16);
    s += __shfl_xor(s, 32);
    Lr = Lr * al + s;
    M = Mn;
    {
      uint2 u;
      u.x = (uint_t)f2bf(e0) | ((uint_t)f2bf(e1) << 16);
      u.y = (uint_t)f2bf(e2) | ((uint_t)f2bf(e3) << 16);
      *(uint2*)&Sp[(16 * w + l16) * 40 + quad * 4] = u;
      uint2 v;
      v.x = (uint_t)f2bf(e4) | ((uint_t)f2bf(e5) << 16);
      v.y = (uint_t)f2bf(e6) | ((uint_t)f2bf(e7) << 16);
      *(uint2*)&Sp[(16 * w + l16) * 40 + 16 + quad * 4] = v;
      if (quad == 0) Al[16 * w + l16] = al;
    }
    __syncthreads();   // B: Sp/Al visible; all waves done reading Ej
    // restage Ej for T+1 (nobody reads Ej until next A, which drains vmcnt)
    if (T < 49) {
#pragma unroll
      for (int i = 0; i < 4; ++i)
        async_ld16(ejb + (size_t)(T + 1) * 8192 + (4 * w + i) * 512 + l * 8,
                   &Ej[(4 * w + i) * 512]);
    }
    // ---- rescale O (alpha of row 16mt+quad*4+r via Al broadcast reads) ----
#pragma unroll
    for (int mt = 0; mt < 4; ++mt) {
      f32x4 a4 = *(const f32x4*)&Al[16 * mt + quad * 4];
#pragma unroll
      for (int nt = 0; nt < 4; ++nt)
#pragma unroll
        for (int r = 0; r < 4; ++r) O[mt][nt][r] *= a4[r];
    }
    // ---- PV: O[p=16mt+quad*4+r][c=64w+16nt+l16] ----
#pragma unroll
    for (int mt = 0; mt < 4; ++mt) {
      short8 Ap = *(const short8*)&Sp[(16 * mt + l16) * 40 + quad * 8];
#pragma unroll
      for (int nt = 0; nt < 4; ++nt)
        O[mt][nt] = __builtin_amdgcn_mfma_f32_16x16x32_bf16(Ap, Bv[nt], O[mt][nt], 0, 0, 0);
    }
  }
  // ---- publish 1/L, then epilogue ----
  __syncthreads();
  if (quad == 0) Linv[16 * w + l16] = 1.f / Lr;
  __syncthreads();
  float* ao = agg_t + (((size_t)jidx * NBB + nb) * PP + p0) * CC;
#pragma unroll
  for (int mt = 0; mt < 4; ++mt) {
    f32x4 li = *(const f32x4*)&Linv[16 * mt + quad * 4];
#pragma unroll
    for (int r = 0; r < 4; ++r) {
      float* dst = ao + (size_t)(16 * mt + quad * 4 + r) * CC + 64 * w + l16;
#pragma unroll
      for (int nt = 0; nt < 4; ++nt) dst[16 * nt] = O[mt][nt][r] * li[r];
    }
  }
}

// ---- conv prep ----

// reorder conv weights [M][512][3][3] fp32 -> [M][9][512] bf16
__global__ void k_wrep(const float* __restrict__ w, ushort_t* __restrict__ wr) {
  int i = blockIdx.x * 256 + threadIdx.x;   // M*9*512
  int ci = i & 511;
  int rest = i >> 9;                        // co*9 + tap
  int tp = rest % 9, co = rest / 9;
  wr[i] = f2bf(w[((size_t)co * 512 + ci) * 9 + tp]);
}

__global__ void k_pad_zero(ushort_t* __restrict__ xpad) {
  int i = blockIdx.x * 256 + threadIdx.x;   // 12*1764*512
  xpad[i] = 0;
}

// interior rows, ch 0..255 <- agg_t[0]+agg_t[1]  (both already [px][c])
__global__ void k_pad_agg(const float* __restrict__ agg_t, ushort_t* __restrict__ xpad) {
  int i = blockIdx.x * 256 + threadIdx.x;   // 12*1600*256
  int c = i & 255;
  int rest = i >> 8;
  int px = rest % PP, nb = rest / PP;
  int y = px / 40, x = px - y * 40;
  size_t src = ((size_t)nb * PP + px) * CC + c;
  float v = agg_t[src] + agg_t[(size_t)NBB * PP * CC + src];
  xpad[((size_t)nb * PAD + (y + 1) * 42 + (x + 1)) * C2 + c] = f2bf(v);
}

// interior rows, ch 256..511 <- transpose of srcA [nb][256][1600]
// MODE 0: val = h[c][px];  MODE 1: val = h[c][px] * r[c][px]
template <int MODE>
__global__ void k_pad_tr(const float* __restrict__ srcA, const float* __restrict__ srcB,
                         ushort_t* __restrict__ xpad) {
  __shared__ float tile[32][33];
  int nb = blockIdx.z;
  int c0 = blockIdx.y * 32;
  int pp0 = blockIdx.x * 32;
  int tx = threadIdx.x & 31, ty = threadIdx.x >> 5;
#pragma unroll
  for (int i = 0; i < 4; ++i) {
    int c = c0 + ty + 8 * i;
    float v = srcA[((size_t)nb * CC + c) * PP + pp0 + tx];
    if (MODE == 1) v *= srcB[((size_t)nb * C2 + c) * PP + pp0 + tx];  // r-gate
    tile[ty + 8 * i][tx] = v;
  }
  __syncthreads();
#pragma unroll
  for (int i = 0; i < 4; ++i) {
    int px = pp0 + ty + 8 * i;
    int y = px / 40, x = px - y * 40;
    xpad[((size_t)nb * PAD + (y + 1) * 42 + (x + 1)) * C2 + CC + c0 + tx] =
        f2bf(tile[tx][ty + 8 * i]);
  }
}

// Implicit-GEMM conv3x3, M=co, N=px(1600), K=9 taps x 512 ci.
// Block: 128co x 128px, 4 waves (2x2), each 64x64 (4x4 16x16x32 frags).
//
// R6 post-mortem: old loop was {barrier; issue 4 global_load_lds; barrier
// (vmcnt(0) drain); compute} x 144 -- load latency (~300cy L2) fully exposed
// every iteration, and the grid (624 blocks / 256 CU = 2.4 blocks/CU) is too
// small for cross-block hiding. MfmaUtil 25% == 80cy MFMA / ~320cy iter.
// Fix: DOUBLE-BUFFERED staging, ONE barrier per iteration:
//   stage(buf0, it0)
//   loop: barrier (drains my loads for buf[cur]; all waves done reading
//         buf[cur^1]) -> stage(buf[cur^1], it+1) -> compute(buf[cur])
// Loads get a full compute phase + barrier of cover; barrier count halves.
// LDS 16->32 KB (irrelevant: grid-limited). Same data, same swizzles.
//
// ACT 0: out = sigmoid(acc+bias) -> gates [nb][512][1600]
// ACT 1: v = tanh(acc+bias); z = zsrc[256+co]; out(nodes) = (1-z)h + z*v
template <int ACT>
__global__ __launch_bounds__(256) void k_conv_mfma(
    const ushort_t* __restrict__ xpad,   // [12][1764][512]
    const ushort_t* __restrict__ wr,     // [M][9*512]
    const float* __restrict__ bias,      // [M]
    const float* __restrict__ zsrc,      // gates (ACT1)
    float* __restrict__ out)
{
  __shared__ ushort_t Asm[2][128 * 32];
  __shared__ ushort_t Bsm[2][128 * 32];
  const int t = threadIdx.x;
  const int w = t >> 6, l = t & 63, quad = l >> 4, l16 = l & 15;
  const int nb = blockIdx.z;
  const int m0 = blockIdx.y * 128;
  const int px0 = blockIdx.x * 128;
  const int wm = (w >> 1) * 64, wn = (w & 1) * 64;

  // --- staging source setup (lane l covers rows 32w + l/4 and +16) ---
  const int lr = l >> 2;
  const int swf = (lr ^ (lr >> 2)) & 3;          // fill-side XOR swizzle
  const int lk = ((l & 3) ^ swf) * 8;            // k-part (shorts)
  const ushort_t* wsrc = wr + (size_t)(m0 + 32 * w + lr) * 4608 + lk;
  int pxa = px0 + 32 * w + lr;      if (pxa > 1599) pxa = 1599;
  int pxb = pxa + 16;               if (pxb > 1599) pxb = 1599;
  {
    int d = px0 + 32 * w + 16 + lr; if (d <= 1599) pxb = d;
  }
  const int ya = pxa / 40, xa = pxa - ya * 40;
  const int yb = pxb / 40, xb = pxb - yb * 40;
  const ushort_t* bsrc_a = xpad + ((size_t)nb * PAD + ya * 42 + xa) * C2 + lk;
  const ushort_t* bsrc_b = xpad + ((size_t)nb * PAD + yb * 42 + xb) * C2 + lk;

  // --- frag-read swizzle (row&15 == l16 on both A and B) ---
  const int swr = (l16 ^ (l16 >> 2)) & 3;
  const int fk = ((quad ^ swr) * 8);

  f32x4 acc[4][4];
#pragma unroll
  for (int mt = 0; mt < 4; ++mt)
#pragma unroll
    for (int nt = 0; nt < 4; ++nt)
#pragma unroll
      for (int r = 0; r < 4; ++r) acc[mt][nt][r] = 0.f;

  // it = tap*16 + c-chunk; tap = it>>4, cc = (it&15)*32 shorts
  // LDS dst is wave-uniform base; HW adds lane*16B.
  auto stage = [&](int buf, int it) {
    int tap = it >> 4;
    int cc = (it & 15) << 5;
    int ky = tap / 3, kx = tap - ky * 3;
    int boff = (ky * 42 + kx) * C2 + cc;
    const ushort_t* wtap = wsrc + tap * 512 + cc;
    async_ld16(wtap, &Asm[buf][w * 1024]);
    async_ld16(wtap + 16 * 4608, &Asm[buf][w * 1024 + 512]);
    async_ld16(bsrc_a + boff, &Bsm[buf][w * 1024]);
    async_ld16(bsrc_b + boff, &Bsm[buf][w * 1024 + 512]);
  };

  stage(0, 0);
  int cur = 0;
#pragma unroll 1
  for (int it = 0; it < 144; ++it) {
    __syncthreads();   // drains vmcnt -> buf[cur] landed; all waves done with buf[cur^1]
    if (it + 1 < 144) stage(cur ^ 1, it + 1);
    short8 Af[4], Bf[4];
#pragma unroll
    for (int mt = 0; mt < 4; ++mt)
      Af[mt] = *(const short8*)(&Asm[cur][0] + (wm + mt * 16 + l16) * 32 + fk);
#pragma unroll
    for (int nt = 0; nt < 4; ++nt)
      Bf[nt] = *(const short8*)(&Bsm[cur][0] + (wn + nt * 16 + l16) * 32 + fk);
#pragma unroll
    for (int mt = 0; mt < 4; ++mt)
#pragma unroll
      for (int nt = 0; nt < 4; ++nt)
        acc[mt][nt] = __builtin_amdgcn_mfma_f32_16x16x32_bf16(Af[mt], Bf[nt], acc[mt][nt], 0, 0, 0);
    cur ^= 1;
  }

  // --- epilogue ---
#pragma unroll
  for (int mt = 0; mt < 4; ++mt) {
#pragma unroll
    for (int r = 0; r < 4; ++r) {
      int co = m0 + wm + mt * 16 + quad * 4 + r;
      float bv = bias[co];
#pragma unroll
      for (int nt = 0; nt < 4; ++nt) {
        int px = px0 + wn + nt * 16 + l16;
        if (px >= PP) continue;
        float v = acc[mt][nt][r] + bv;
        if (ACT == 0) {
          out[((size_t)nb * C2 + co) * PP + px] = 1.f / (1.f + __expf(-v));
        } else {
          v = tanhf(v);
          float z = zsrc[((size_t)nb * C2 + CC + co) * PP + px];
          float* hp = out + ((size_t)nb * CC + co) * PP + px;
          float h = *hp;
          *hp = (1.f - z) * h + z * v;
        }
      }
    }
  }
}

extern "C" void kernel_launch(void* const* d_in, const int* in_sizes, int n_in,
                              void* d_out, int out_size, void* d_ws, size_t ws_size,
                              hipStream_t stream) {
  const float* nodes_in = (const float*)d_in[0];
  const float* tw = (const float*)d_in[1];
  const float* tb = (const float*)d_in[2];
  const float* gw = (const float*)d_in[3];
  const float* gb = (const float*)d_in[4];
  const float* cw = (const float*)d_in[5];
  const float* cb = (const float*)d_in[6];

  float* nodes = (float*)d_out;                      // fp32 state [12][256][1600]
  char* ws = (char*)d_ws;
  // ---- layout (ws >= 98.3 MB) ----
  // attn phase: R0 nodes_bf_t 9.83 | R1 th_t 9.83 | R2 vf 19.66 | R3 agg_t 39.32
  // conv phase: R1+R2 xh_pad 21.68 | R3 gates 39.32
  // persistent:  78.64.. w_g_r 4.72 | 83.36.. w_c_r 2.36   (pass-invariant)
  ushort_t* nodes_bf_t = (ushort_t*)ws;
  ushort_t* th_t  = (ushort_t*)(ws + 9830400);
  ushort_t* vf    = (ushort_t*)(ws + 19660800);
  float*    agg_t = (float*)(ws + 39321600);
  ushort_t* xh_pad = (ushort_t*)(ws + 9830400);      // 12*1764*512*2 = 21,676,032
  float*    gates = (float*)(ws + 39321600);
  ushort_t* w_g_r = (ushort_t*)(ws + 78643200);      // 4,718,592 B
  ushort_t* w_c_r = (ushort_t*)(ws + 83361792);      // 2,359,296 B (ends 85.7 MB)

  k_copy<<<NODESZ / 256, 256, 0, stream>>>(nodes_in, nodes);
  k_wrep<<<(C2 * 9 * C2) / 256, 256, 0, stream>>>(gw, w_g_r);
  k_wrep<<<(CC * 9 * C2) / 256, 256, 0, stream>>>(cw, w_c_r);
  for (int pass = 0; pass < 2; ++pass) {
    // ---- attention ----
    k_theta<<<dim3(5, NBB * (CC / TO)), 320, 0, stream>>>(nodes, tw, tb, th_t);
    k_to_bf_t<<<dim3(50, 8, NBB), 256, 0, stream>>>(nodes, nodes_bf_t);
    k_prep_vf<<<dim3(50, 24), 256, 0, stream>>>(nodes, vf);
    k_attn_mfma<<<dim3(25, NBB, 2), 256, 0, stream>>>(nodes_bf_t, th_t, vf, agg_t);
    // ---- conv prep (attn scratch now dead) ----
    k_pad_zero<<<(NBB * PAD * C2) / 256, 256, 0, stream>>>(xh_pad);
    k_pad_agg<<<(NBB * PP * CC) / 256, 256, 0, stream>>>(agg_t, xh_pad);
    k_pad_tr<0><<<dim3(50, 8, NBB), 256, 0, stream>>>(nodes, nullptr, xh_pad);
    // ---- gates conv ----
    k_conv_mfma<0><<<dim3(13, 4, NBB), 256, 0, stream>>>(xh_pad, w_g_r, gb, nullptr, gates);
    // ---- r*h into xh_pad high channels ----
    k_pad_tr<1><<<dim3(50, 8, NBB), 256, 0, stream>>>(nodes, gates, xh_pad);
    // ---- cand conv + fused GRU update ----
    k_conv_mfma<1><<<dim3(13, 2, NBB), 256, 0, stream>>>(xh_pad, w_c_r, cb, gates, nodes);
  }
}

// Round 8
// 1100.522 us; speedup vs baseline: 1.0099x; 1.0099x over previous
//
#include <hip/hip_runtime.h>
#include <hip/hip_bf16.h>
#include <math.h>

#define NN 3
#define BB 4
#define CC 256
#define C2 512
#define HH 40
#define WW 40
#define PP 1600
#define NBB 12                  // NN*BB
#define NODESZ (NBB*CC*PP)      // 4,915,200
#define TO 16                   // theta: output channels per block
#define PAD 1764                // 42*42 padded pixels

typedef short short8 __attribute__((ext_vector_type(8)));
typedef float f32x4 __attribute__((ext_vector_type(4)));
typedef unsigned short ushort_t;
typedef unsigned int uint_t;

__device__ __forceinline__ ushort_t f2bf(float x) {
  union { float f; uint_t u; } v; v.f = x;
  uint_t r = v.u + 0x7fff + ((v.u >> 16) & 1);
  return (ushort_t)(r >> 16);
}

__device__ __forceinline__ void async_ld16(const ushort_t* g, ushort_t* l) {
  __builtin_amdgcn_global_load_lds(
      (const __attribute__((address_space(1))) uint_t*)g,
      (__attribute__((address_space(3))) uint_t*)l, 16, 0, 0);
}

__global__ void k_copy(const float* __restrict__ in, float* __restrict__ out) {
  int i = blockIdx.x * 256 + threadIdx.x;
  out[i] = in[i];
}

// th_t[nb][p][c] (bf16) = tb[o] + sum_c tw[o,c] * nodes[nb,c,p]
__global__ void k_theta(const float* __restrict__ nodes, const float* __restrict__ tw,
                        const float* __restrict__ tb, ushort_t* __restrict__ th_t) {
  __shared__ float w[TO * CC];
  int t = threadIdx.x;
  int nb = blockIdx.y / (CC / TO);
  int o0 = (blockIdx.y % (CC / TO)) * TO;
  for (int i = t; i < TO * CC; i += 320) w[i] = tw[(o0 + (i >> 8)) * CC + (i & 255)];
  __syncthreads();
  int p = blockIdx.x * 320 + t;
  const float* src = nodes + nb * CC * PP + p;
  float acc[TO];
#pragma unroll
  for (int o = 0; o < TO; ++o) acc[o] = tb[o0 + o];
  for (int c = 0; c < CC; c += 4) {
    float v0 = src[c * PP], v1 = src[(c + 1) * PP], v2 = src[(c + 2) * PP], v3 = src[(c + 3) * PP];
#pragma unroll
    for (int o = 0; o < TO; ++o) {
      const float4 ww = *(const float4*)(w + o * CC + c);
      acc[o] += ww.x * v0 + ww.y * v1 + ww.z * v2 + ww.w * v3;
    }
  }
  size_t base = ((size_t)nb * PP + p) * CC + o0;
#pragma unroll
  for (int o = 0; o < TO; o += 2) {
    uint_t lo = f2bf(acc[o]), hi = f2bf(acc[o + 1]);
    *(uint_t*)&th_t[base + o] = lo | (hi << 16);
  }
}

// nodes [12][256][1600] fp32 -> nodes_bf_t [12][1600][256] bf16 (transpose),
// with 16B-chunk XOR swizzle within each row: c' = c ^ ((q&7)<<3).
// (Consumed only by k_attn_mfma, which un-XORs on its LDS frag reads.)
__global__ void k_to_bf_t(const float* __restrict__ src, ushort_t* __restrict__ dst) {
  __shared__ float tile[32][33];
  int nb = blockIdx.z;
  int c0 = blockIdx.y * 32;
  int pp0 = blockIdx.x * 32;
  int tx = threadIdx.x & 31, ty = threadIdx.x >> 5;
#pragma unroll
  for (int i = 0; i < 4; ++i)
    tile[ty + 8 * i][tx] = src[((size_t)nb * CC + c0 + ty + 8 * i) * PP + pp0 + tx];
  __syncthreads();
#pragma unroll
  for (int i = 0; i < 4; ++i) {
    int q = pp0 + ty + 8 * i;
    int c = c0 + tx;
    int cs = c ^ ((q & 7) << 3);
    dst[((size_t)nb * PP + q) * CC + cs] = f2bf(tile[tx][ty + 8 * i]);
  }
}

// vf frag-major bf16: vf[eb][T][nt][lane(quad,l16)][j]
//   = nodes[recv][c][p] + nodes[send][c][p],  c = 16nt + l16, p = 32T + quad*8 + j
// Each (T,nt) PV B-fragment = contiguous 1KB, one coalesced load in attn.
__global__ void k_prep_vf(const float* __restrict__ nodes, ushort_t* __restrict__ vf) {
  int T = blockIdx.x;                   // 0..49
  int eb = blockIdx.y;                  // 0..23
  int e = eb >> 2, b = eb & 3;
  int n = e >> 1, jidx = e & 1;
  int js = jidx + (jidx >= n ? 1 : 0);
  const float* s0 = nodes + (size_t)(n * BB + b) * CC * PP;
  const float* s1 = nodes + (size_t)(js * BB + b) * CC * PP;
  ushort_t* dst = vf + ((size_t)eb * 50 + T) * 8192;
  int t = threadIdx.x;
#pragma unroll
  for (int k = 0; k < 4; ++k) {
    int cid = t + 256 * k;              // 0..1023 (16 nt x 64 lanes)
    int nt = cid >> 6, l = cid & 63;
    int quad = l >> 4, l16 = l & 15;
    int c = 16 * nt + l16;
    int p = 32 * T + quad * 8;
    const float4* a0 = (const float4*)(s0 + (size_t)c * PP + p);
    const float4* a1 = (const float4*)(s1 + (size_t)c * PP + p);
    float4 x0 = a0[0], x1 = a0[1];
    float4 y0 = a1[0], y1 = a1[1];
    short8 o;
    o[0] = (short)f2bf(x0.x + y0.x); o[1] = (short)f2bf(x0.y + y0.y);
    o[2] = (short)f2bf(x0.z + y0.z); o[3] = (short)f2bf(x0.w + y0.w);
    o[4] = (short)f2bf(x1.x + y1.x); o[5] = (short)f2bf(x1.y + y1.y);
    o[6] = (short)f2bf(x1.z + y1.z); o[7] = (short)f2bf(x1.w + y1.w);
    *(short8*)(dst + (size_t)cid * 8) = o;
  }
}

// Flash attention, 64-p block, 4 waves, swapped-S softmax.
// R8: + XCD-aware bijective block swizzle. All 25 p0-blocks of one (nb,jidx)
// share the same 1.64 MB ej+vf stream; default round-robin sprays them over
// 8 XCDs (every XCD fetches every stream via L3 -- the ~9 TB/s fabric wall
// from R5). Chunked remap gives each XCD 3 complete (nb,jidx) groups ->
// streams become L2-resident (3x1.64 MB vs 4 MB), reused 25x from L2.
// nwg = 600, 600%8==0 -> wk = (F%8)*75 + F/8 is bijective.
__global__ __launch_bounds__(256, 2) void k_attn_mfma(
    const ushort_t* __restrict__ nodes_bf_t,  // [12][1600][256] chunk-swizzled
    const ushort_t* __restrict__ th_t,        // [12][1600][256] plain
    const ushort_t* __restrict__ vf,          // [24][50][16][512] frag-major
    float* __restrict__ agg_t)                // [2][12][1600][256]
{
  __shared__ ushort_t Ej[32 * 256];   // 16 KB
  __shared__ ushort_t Sp[64 * 40];    // 5 KB (rows padded to 40 u16 = 80B)
  __shared__ float Al[64];
  __shared__ float Linv[64];

  const int t = threadIdx.x;
  const int w = t >> 6;               // 0..3
  const int l = t & 63;
  const int quad = l >> 4;
  const int l16 = l & 15;
  // ---- XCD-aware remap (perf-only; mapping assumption xcd = flat%8) ----
  const int F = blockIdx.x + 25 * (blockIdx.y + 12 * blockIdx.z);
  const int wk = (F & 7) * 75 + (F >> 3);        // bijective: 600 = 8*75
  const int p0 = (wk % 25) * 64;
  const int nb = (wk / 25) % 12;
  const int jidx = wk / 300;
  const int n = nb >> 2, b = nb & 3;
  const int e = n * 2 + jidx;
  const int js = jidx + (jidx >= n ? 1 : 0);
  const int eb = e * BB + b;

  const ushort_t* ejb = nodes_bf_t + ((size_t)(js * BB + b) * PP) * CC;  // [q][c-swz]
  const ushort_t* vbase = vf + (size_t)eb * 50 * 8192;

  // th B-frags for this wave's rows p = p0 + 16w + l16 (resident all iters)
  short8 Ath[8];
  {
    const ushort_t* arow = th_t + ((size_t)nb * PP + p0 + 16 * w + l16) * CC + quad * 8;
#pragma unroll
    for (int ks = 0; ks < 8; ++ks) Ath[ks] = *(const short8*)(arow + ks * 32);
  }

  float M = -3.0e38f, Lr = 0.f;       // per-lane: this lane's p-row state
  f32x4 O[4][4];
#pragma unroll
  for (int mt = 0; mt < 4; ++mt)
#pragma unroll
    for (int nt = 0; nt < 4; ++nt)
#pragma unroll
      for (int r = 0; r < 4; ++r) O[mt][nt][r] = 0.f;

  // prologue: stage q-tile 0 (16 chunks of 1KB, wave w does 4)
#pragma unroll
  for (int i = 0; i < 4; ++i)
    async_ld16(ejb + (4 * w + i) * 512 + l * 8, &Ej[(4 * w + i) * 512]);

  for (int T = 0; T < 50; ++T) {
    __syncthreads();   // A: Ej[T] landed (barrier drains vmcnt); Sp/Al free
    // V frags for this iter (coalesced 1KB each); vmcnt-covered by S+softmax
    short8 Bv[4];
    {
      const ushort_t* vt = vbase + (size_t)T * 8192;
#pragma unroll
      for (int nt = 0; nt < 4; ++nt)
        Bv[nt] = *(const short8*)(vt + (4 * w + nt) * 512 + l * 8);
    }
    // ---- swapped S-GEMM: S^T[q][p], rows q = quad*4+r (+16), cols p = l16 ----
    f32x4 S0, S1;
#pragma unroll
    for (int r = 0; r < 4; ++r) { S0[r] = 0.f; S1[r] = 0.f; }
#pragma unroll
    for (int ks = 0; ks < 8; ++ks) {
      int ch0 = (((ks * 4 + quad) ^ (l16 & 7)) << 3);
      short8 A0 = *(const short8*)(Ej + l16 * CC + ch0);
      short8 A1 = *(const short8*)(Ej + (16 + l16) * CC + ch0);
      S0 = __builtin_amdgcn_mfma_f32_16x16x32_bf16(A0, Ath[ks], S0, 0, 0, 0);
      S1 = __builtin_amdgcn_mfma_f32_16x16x32_bf16(A1, Ath[ks], S1, 0, 0, 0);
    }
    // ---- softmax: 8 in-lane q-values for p = p0+16w+l16; reduce across quads ----
    float m = fmaxf(fmaxf(fmaxf(S0[0], S0[1]), fmaxf(S0[2], S0[3])),
                    fmaxf(fmaxf(S1[0], S1[1]), fmaxf(S1[2], S1[3])));
    m = fmaxf(m, __shfl_xor(m, 16));
    m = fmaxf(m, __shfl_xor(m, 32));
    float Mn = fmaxf(M, m);
    float al = __expf(M - Mn);
    float e0 = __expf(S0[0] - Mn), e1 = __expf(S0[1] - Mn);
    float e2 = __expf(S0[2] - Mn), e3 = __expf(S0[3] - Mn);
    float e4 = __expf(S1[0] - Mn), e5 = __expf(S1[1] - Mn);
    float e6 = __expf(S1[2] - Mn), e7 = __expf(S1[3] - Mn);
    float s = ((e0 + e1) + (e2 + e3)) + ((e4 + e5) + (e6 + e7));
    s += __shfl_xor(s, 16);
    s += __shfl_xor(s, 32);
    Lr = Lr * al + s;
    M = Mn;
    {
      uint2 u;
      u.x = (uint_t)f2bf(e0) | ((uint_t)f2bf(e1) << 16);
      u.y = (uint_t)f2bf(e2) | ((uint_t)f2bf(e3) << 16);
      *(uint2*)&Sp[(16 * w + l16) * 40 + quad * 4] = u;
      uint2 v;
      v.x = (uint_t)f2bf(e4) | ((uint_t)f2bf(e5) << 16);
      v.y = (uint_t)f2bf(e6) | ((uint_t)f2bf(e7) << 16);
      *(uint2*)&Sp[(16 * w + l16) * 40 + 16 + quad * 4] = v;
      if (quad == 0) Al[16 * w + l16] = al;
    }
    __syncthreads();   // B: Sp/Al visible; all waves done reading Ej
    // restage Ej for T+1 (nobody reads Ej until next A, which drains vmcnt)
    if (T < 49) {
#pragma unroll
      for (int i = 0; i < 4; ++i)
        async_ld16(ejb + (size_t)(T + 1) * 8192 + (4 * w + i) * 512 + l * 8,
                   &Ej[(4 * w + i) * 512]);
    }
    // ---- rescale O (alpha of row 16mt+quad*4+r via Al broadcast reads) ----
#pragma unroll
    for (int mt = 0; mt < 4; ++mt) {
      f32x4 a4 = *(const f32x4*)&Al[16 * mt + quad * 4];
#pragma unroll
      for (int nt = 0; nt < 4; ++nt)
#pragma unroll
        for (int r = 0; r < 4; ++r) O[mt][nt][r] *= a4[r];
    }
    // ---- PV: O[p=16mt+quad*4+r][c=64w+16nt+l16] ----
#pragma unroll
    for (int mt = 0; mt < 4; ++mt) {
      short8 Ap = *(const short8*)&Sp[(16 * mt + l16) * 40 + quad * 8];
#pragma unroll
      for (int nt = 0; nt < 4; ++nt)
        O[mt][nt] = __builtin_amdgcn_mfma_f32_16x16x32_bf16(Ap, Bv[nt], O[mt][nt], 0, 0, 0);
    }
  }
  // ---- publish 1/L, then epilogue ----
  __syncthreads();
  if (quad == 0) Linv[16 * w + l16] = 1.f / Lr;
  __syncthreads();
  float* ao = agg_t + (((size_t)jidx * NBB + nb) * PP + p0) * CC;
#pragma unroll
  for (int mt = 0; mt < 4; ++mt) {
    f32x4 li = *(const f32x4*)&Linv[16 * mt + quad * 4];
#pragma unroll
    for (int r = 0; r < 4; ++r) {
      float* dst = ao + (size_t)(16 * mt + quad * 4 + r) * CC + 64 * w + l16;
#pragma unroll
      for (int nt = 0; nt < 4; ++nt) dst[16 * nt] = O[mt][nt][r] * li[r];
    }
  }
}

// ---- conv prep ----

// reorder conv weights [M][512][3][3] fp32 -> [M][9][512] bf16
__global__ void k_wrep(const float* __restrict__ w, ushort_t* __restrict__ wr) {
  int i = blockIdx.x * 256 + threadIdx.x;   // M*9*512
  int ci = i & 511;
  int rest = i >> 9;                        // co*9 + tap
  int tp = rest % 9, co = rest / 9;
  wr[i] = f2bf(w[((size_t)co * 512 + ci) * 9 + tp]);
}

__global__ void k_pad_zero(ushort_t* __restrict__ xpad) {
  int i = blockIdx.x * 256 + threadIdx.x;   // 12*1764*512
  xpad[i] = 0;
}

// interior rows, ch 0..255 <- agg_t[0]+agg_t[1]  (both already [px][c])
__global__ void k_pad_agg(const float* __restrict__ agg_t, ushort_t* __restrict__ xpad) {
  int i = blockIdx.x * 256 + threadIdx.x;   // 12*1600*256
  int c = i & 255;
  int rest = i >> 8;
  int px = rest % PP, nb = rest / PP;
  int y = px / 40, x = px - y * 40;
  size_t src = ((size_t)nb * PP + px) * CC + c;
  float v = agg_t[src] + agg_t[(size_t)NBB * PP * CC + src];
  xpad[((size_t)nb * PAD + (y + 1) * 42 + (x + 1)) * C2 + c] = f2bf(v);
}

// interior rows, ch 256..511 <- transpose of srcA [nb][256][1600]
// MODE 0: val = h[c][px];  MODE 1: val = h[c][px] * r[c][px]
template <int MODE>
__global__ void k_pad_tr(const float* __restrict__ srcA, const float* __restrict__ srcB,
                         ushort_t* __restrict__ xpad) {
  __shared__ float tile[32][33];
  int nb = blockIdx.z;
  int c0 = blockIdx.y * 32;
  int pp0 = blockIdx.x * 32;
  int tx = threadIdx.x & 31, ty = threadIdx.x >> 5;
#pragma unroll
  for (int i = 0; i < 4; ++i) {
    int c = c0 + ty + 8 * i;
    float v = srcA[((size_t)nb * CC + c) * PP + pp0 + tx];
    if (MODE == 1) v *= srcB[((size_t)nb * C2 + c) * PP + pp0 + tx];  // r-gate
    tile[ty + 8 * i][tx] = v;
  }
  __syncthreads();
#pragma unroll
  for (int i = 0; i < 4; ++i) {
    int px = pp0 + ty + 8 * i;
    int y = px / 40, x = px - y * 40;
    xpad[((size_t)nb * PAD + (y + 1) * 42 + (x + 1)) * C2 + CC + c0 + tx] =
        f2bf(tile[tx][ty + 8 * i]);
  }
}

// Implicit-GEMM conv3x3, M=co, N=px(1600), K=9 taps x 512 ci.
// Block: 128co x 128px, 4 waves (2x2), each 64x64 (4x4 16x16x32 frags).
//
// R7 post-mortem: double-buffer was NEUTRAL. FETCH 371 MB @153us = staging
// loads mostly MISS L2 (default round-robin spreads every sharing group over
// all 8 XCDs; per-XCD L2 is 4 MB). HBM-miss latency ~900cy >> 200cy compute
// cover -> 1-deep pipeline can't hide it. Fix the HIT RATE, not the pipeline:
// R8 XCD-aware bijective remap, work order x + 13*(z + 12*y): each XCD chunk
// = all 13 px-blocks x 6 nb at ONE m-panel -> 1.18 MB weight panel L2-resident
// (reused 78x), xpad streams with tap-locality. nwg 624/312, both %8==0.
//
// ACT 0: out = sigmoid(acc+bias) -> gates [nb][512][1600]
// ACT 1: v = tanh(acc+bias); z = zsrc[256+co]; out(nodes) = (1-z)h + z*v
template <int ACT>
__global__ __launch_bounds__(256) void k_conv_mfma(
    const ushort_t* __restrict__ xpad,   // [12][1764][512]
    const ushort_t* __restrict__ wr,     // [M][9*512]
    const float* __restrict__ bias,      // [M]
    const float* __restrict__ zsrc,      // gates (ACT1)
    float* __restrict__ out)
{
  __shared__ ushort_t Asm[2][128 * 32];
  __shared__ ushort_t Bsm[2][128 * 32];
  const int t = threadIdx.x;
  const int w = t >> 6, l = t & 63, quad = l >> 4, l16 = l & 15;
  // ---- XCD-aware remap (perf-only) ----
  const int gy = gridDim.y;                       // 4 (gates) or 2 (cand)
  const int F = blockIdx.x + 13 * (blockIdx.y + gy * blockIdx.z);
  const int cpx = (13 * gy * 12) >> 3;            // 78 or 39
  const int wk = (F & 7) * cpx + (F >> 3);        // bijective: nwg%8==0
  const int xw = wk % 13;
  const int rest = wk / 13;
  const int nb = rest % 12;
  const int m0 = (rest / 12) * 128;
  const int px0 = xw * 128;
  const int wm = (w >> 1) * 64, wn = (w & 1) * 64;

  // --- staging source setup (lane l covers rows 32w + l/4 and +16) ---
  const int lr = l >> 2;
  const int swf = (lr ^ (lr >> 2)) & 3;          // fill-side XOR swizzle
  const int lk = ((l & 3) ^ swf) * 8;            // k-part (shorts)
  const ushort_t* wsrc = wr + (size_t)(m0 + 32 * w + lr) * 4608 + lk;
  int pxa = px0 + 32 * w + lr;      if (pxa > 1599) pxa = 1599;
  int pxb = pxa + 16;               if (pxb > 1599) pxb = 1599;
  {
    int d = px0 + 32 * w + 16 + lr; if (d <= 1599) pxb = d;
  }
  const int ya = pxa / 40, xa = pxa - ya * 40;
  const int yb = pxb / 40, xb = pxb - yb * 40;
  const ushort_t* bsrc_a = xpad + ((size_t)nb * PAD + ya * 42 + xa) * C2 + lk;
  const ushort_t* bsrc_b = xpad + ((size_t)nb * PAD + yb * 42 + xb) * C2 + lk;

  // --- frag-read swizzle (row&15 == l16 on both A and B) ---
  const int swr = (l16 ^ (l16 >> 2)) & 3;
  const int fk = ((quad ^ swr) * 8);

  f32x4 acc[4][4];
#pragma unroll
  for (int mt = 0; mt < 4; ++mt)
#pragma unroll
    for (int nt = 0; nt < 4; ++nt)
#pragma unroll
      for (int r = 0; r < 4; ++r) acc[mt][nt][r] = 0.f;

  // it = tap*16 + c-chunk; tap = it>>4, cc = (it&15)*32 shorts
  // LDS dst is wave-uniform base; HW adds lane*16B.
  auto stage = [&](int buf, int it) {
    int tap = it >> 4;
    int cc = (it & 15) << 5;
    int ky = tap / 3, kx = tap - ky * 3;
    int boff = (ky * 42 + kx) * C2 + cc;
    const ushort_t* wtap = wsrc + tap * 512 + cc;
    async_ld16(wtap, &Asm[buf][w * 1024]);
    async_ld16(wtap + 16 * 4608, &Asm[buf][w * 1024 + 512]);
    async_ld16(bsrc_a + boff, &Bsm[buf][w * 1024]);
    async_ld16(bsrc_b + boff, &Bsm[buf][w * 1024 + 512]);
  };

  stage(0, 0);
  int cur = 0;
#pragma unroll 1
  for (int it = 0; it < 144; ++it) {
    __syncthreads();   // drains vmcnt -> buf[cur] landed; all waves done with buf[cur^1]
    if (it + 1 < 144) stage(cur ^ 1, it + 1);
    short8 Af[4], Bf[4];
#pragma unroll
    for (int mt = 0; mt < 4; ++mt)
      Af[mt] = *(const short8*)(&Asm[cur][0] + (wm + mt * 16 + l16) * 32 + fk);
#pragma unroll
    for (int nt = 0; nt < 4; ++nt)
      Bf[nt] = *(const short8*)(&Bsm[cur][0] + (wn + nt * 16 + l16) * 32 + fk);
#pragma unroll
    for (int mt = 0; mt < 4; ++mt)
#pragma unroll
      for (int nt = 0; nt < 4; ++nt)
        acc[mt][nt] = __builtin_amdgcn_mfma_f32_16x16x32_bf16(Af[mt], Bf[nt], acc[mt][nt], 0, 0, 0);
    cur ^= 1;
  }

  // --- epilogue ---
#pragma unroll
  for (int mt = 0; mt < 4; ++mt) {
#pragma unroll
    for (int r = 0; r < 4; ++r) {
      int co = m0 + wm + mt * 16 + quad * 4 + r;
      float bv = bias[co];
#pragma unroll
      for (int nt = 0; nt < 4; ++nt) {
        int px = px0 + wn + nt * 16 + l16;
        if (px >= PP) continue;
        float v = acc[mt][nt][r] + bv;
        if (ACT == 0) {
          out[((size_t)nb * C2 + co) * PP + px] = 1.f / (1.f + __expf(-v));
        } else {
          v = tanhf(v);
          float z = zsrc[((size_t)nb * C2 + CC + co) * PP + px];
          float* hp = out + ((size_t)nb * CC + co) * PP + px;
          float h = *hp;
          *hp = (1.f - z) * h + z * v;
        }
      }
    }
  }
}

extern "C" void kernel_launch(void* const* d_in, const int* in_sizes, int n_in,
                              void* d_out, int out_size, void* d_ws, size_t ws_size,
                              hipStream_t stream) {
  const float* nodes_in = (const float*)d_in[0];
  const float* tw = (const float*)d_in[1];
  const float* tb = (const float*)d_in[2];
  const float* gw = (const float*)d_in[3];
  const float* gb = (const float*)d_in[4];
  const float* cw = (const float*)d_in[5];
  const float* cb = (const float*)d_in[6];

  float* nodes = (float*)d_out;                      // fp32 state [12][256][1600]
  char* ws = (char*)d_ws;
  // ---- layout (ws >= 98.3 MB) ----
  // attn phase: R0 nodes_bf_t 9.83 | R1 th_t 9.83 | R2 vf 19.66 | R3 agg_t 39.32
  // conv phase: R1+R2 xh_pad 21.68 | R3 gates 39.32
  // persistent:  78.64.. w_g_r 4.72 | 83.36.. w_c_r 2.36   (pass-invariant)
  ushort_t* nodes_bf_t = (ushort_t*)ws;
  ushort_t* th_t  = (ushort_t*)(ws + 9830400);
  ushort_t* vf    = (ushort_t*)(ws + 19660800);
  float*    agg_t = (float*)(ws + 39321600);
  ushort_t* xh_pad = (ushort_t*)(ws + 9830400);      // 12*1764*512*2 = 21,676,032
  float*    gates = (float*)(ws + 39321600);
  ushort_t* w_g_r = (ushort_t*)(ws + 78643200);      // 4,718,592 B
  ushort_t* w_c_r = (ushort_t*)(ws + 83361792);      // 2,359,296 B (ends 85.7 MB)

  k_copy<<<NODESZ / 256, 256, 0, stream>>>(nodes_in, nodes);
  k_wrep<<<(C2 * 9 * C2) / 256, 256, 0, stream>>>(gw, w_g_r);
  k_wrep<<<(CC * 9 * C2) / 256, 256, 0, stream>>>(cw, w_c_r);
  for (int pass = 0; pass < 2; ++pass) {
    // ---- attention ----
    k_theta<<<dim3(5, NBB * (CC / TO)), 320, 0, stream>>>(nodes, tw, tb, th_t);
    k_to_bf_t<<<dim3(50, 8, NBB), 256, 0, stream>>>(nodes, nodes_bf_t);
    k_prep_vf<<<dim3(50, 24), 256, 0, stream>>>(nodes, vf);
    k_attn_mfma<<<dim3(25, NBB, 2), 256, 0, stream>>>(nodes_bf_t, th_t, vf, agg_t);
    // ---- conv prep (attn scratch now dead) ----
    k_pad_zero<<<(NBB * PAD * C2) / 256, 256, 0, stream>>>(xh_pad);
    k_pad_agg<<<(NBB * PP * CC) / 256, 256, 0, stream>>>(agg_t, xh_pad);
    k_pad_tr<0><<<dim3(50, 8, NBB), 256, 0, stream>>>(nodes, nullptr, xh_pad);
    // ---- gates conv ----
    k_conv_mfma<0><<<dim3(13, 4, NBB), 256, 0, stream>>>(xh_pad, w_g_r, gb, nullptr, gates);
    // ---- r*h into xh_pad high channels ----
    k_pad_tr<1><<<dim3(50, 8, NBB), 256, 0, stream>>>(nodes, gates, xh_pad);
    // ---- cand conv + fused GRU update ----
    k_conv_mfma<1><<<dim3(13, 2, NBB), 256, 0, stream>>>(xh_pad, w_c_r, cb, gates, nodes);
  }
}

// Round 9
// 1078.881 us; speedup vs baseline: 1.0302x; 1.0201x over previous
//
#include <hip/hip_runtime.h>
#include <hip/hip_bf16.h>
#include <math.h>

#define NN 3
#define BB 4
#define CC 256
#define C2 512
#define HH 40
#define WW 40
#define PP 1600
#define NBB 12                  // NN*BB
#define NODESZ (NBB*CC*PP)      // 4,915,200
#define TO 16                   // theta: output channels per block
#define PAD 1764                // 42*42 padded pixels

typedef short short8 __attribute__((ext_vector_type(8)));
typedef float f32x4 __attribute__((ext_vector_type(4)));
typedef unsigned short ushort_t;
typedef unsigned int uint_t;

__device__ __forceinline__ ushort_t f2bf(float x) {
  union { float f; uint_t u; } v; v.f = x;
  uint_t r = v.u + 0x7fff + ((v.u >> 16) & 1);
  return (ushort_t)(r >> 16);
}

__device__ __forceinline__ void async_ld16(const ushort_t* g, ushort_t* l) {
  __builtin_amdgcn_global_load_lds(
      (const __attribute__((address_space(1))) uint_t*)g,
      (__attribute__((address_space(3))) uint_t*)l, 16, 0, 0);
}

__global__ void k_copy(const float* __restrict__ in, float* __restrict__ out) {
  int i = blockIdx.x * 256 + threadIdx.x;
  out[i] = in[i];
}

// th_t[nb][p][c] (bf16) = tb[o] + sum_c tw[o,c] * nodes[nb,c,p]
__global__ void k_theta(const float* __restrict__ nodes, const float* __restrict__ tw,
                        const float* __restrict__ tb, ushort_t* __restrict__ th_t) {
  __shared__ float w[TO * CC];
  int t = threadIdx.x;
  int nb = blockIdx.y / (CC / TO);
  int o0 = (blockIdx.y % (CC / TO)) * TO;
  for (int i = t; i < TO * CC; i += 320) w[i] = tw[(o0 + (i >> 8)) * CC + (i & 255)];
  __syncthreads();
  int p = blockIdx.x * 320 + t;
  const float* src = nodes + nb * CC * PP + p;
  float acc[TO];
#pragma unroll
  for (int o = 0; o < TO; ++o) acc[o] = tb[o0 + o];
  for (int c = 0; c < CC; c += 4) {
    float v0 = src[c * PP], v1 = src[(c + 1) * PP], v2 = src[(c + 2) * PP], v3 = src[(c + 3) * PP];
#pragma unroll
    for (int o = 0; o < TO; ++o) {
      const float4 ww = *(const float4*)(w + o * CC + c);
      acc[o] += ww.x * v0 + ww.y * v1 + ww.z * v2 + ww.w * v3;
    }
  }
  size_t base = ((size_t)nb * PP + p) * CC + o0;
#pragma unroll
  for (int o = 0; o < TO; o += 2) {
    uint_t lo = f2bf(acc[o]), hi = f2bf(acc[o + 1]);
    *(uint_t*)&th_t[base + o] = lo | (hi << 16);
  }
}

// nodes [12][256][1600] fp32 -> nodes_bf_t [12][1600][256] bf16 (transpose),
// with 16B-chunk XOR swizzle within each row: c' = c ^ ((q&7)<<3).
// (Consumed only by k_attn_mfma, which un-XORs on its LDS frag reads.)
__global__ void k_to_bf_t(const float* __restrict__ src, ushort_t* __restrict__ dst) {
  __shared__ float tile[32][33];
  int nb = blockIdx.z;
  int c0 = blockIdx.y * 32;
  int pp0 = blockIdx.x * 32;
  int tx = threadIdx.x & 31, ty = threadIdx.x >> 5;
#pragma unroll
  for (int i = 0; i < 4; ++i)
    tile[ty + 8 * i][tx] = src[((size_t)nb * CC + c0 + ty + 8 * i) * PP + pp0 + tx];
  __syncthreads();
#pragma unroll
  for (int i = 0; i < 4; ++i) {
    int q = pp0 + ty + 8 * i;
    int c = c0 + tx;
    int cs = c ^ ((q & 7) << 3);
    dst[((size_t)nb * PP + q) * CC + cs] = f2bf(tile[tx][ty + 8 * i]);
  }
}

// vf frag-major bf16: vf[eb][T][nt][lane(quad,l16)][j]
//   = nodes[recv][c][p] + nodes[send][c][p],  c = 16nt + l16, p = 32T + quad*8 + j
// Each (T,nt) PV B-fragment = contiguous 1KB, one coalesced load in attn.
__global__ void k_prep_vf(const float* __restrict__ nodes, ushort_t* __restrict__ vf) {
  int T = blockIdx.x;                   // 0..49
  int eb = blockIdx.y;                  // 0..23
  int e = eb >> 2, b = eb & 3;
  int n = e >> 1, jidx = e & 1;
  int js = jidx + (jidx >= n ? 1 : 0);
  const float* s0 = nodes + (size_t)(n * BB + b) * CC * PP;
  const float* s1 = nodes + (size_t)(js * BB + b) * CC * PP;
  ushort_t* dst = vf + ((size_t)eb * 50 + T) * 8192;
  int t = threadIdx.x;
#pragma unroll
  for (int k = 0; k < 4; ++k) {
    int cid = t + 256 * k;              // 0..1023 (16 nt x 64 lanes)
    int nt = cid >> 6, l = cid & 63;
    int quad = l >> 4, l16 = l & 15;
    int c = 16 * nt + l16;
    int p = 32 * T + quad * 8;
    const float4* a0 = (const float4*)(s0 + (size_t)c * PP + p);
    const float4* a1 = (const float4*)(s1 + (size_t)c * PP + p);
    float4 x0 = a0[0], x1 = a0[1];
    float4 y0 = a1[0], y1 = a1[1];
    short8 o;
    o[0] = (short)f2bf(x0.x + y0.x); o[1] = (short)f2bf(x0.y + y0.y);
    o[2] = (short)f2bf(x0.z + y0.z); o[3] = (short)f2bf(x0.w + y0.w);
    o[4] = (short)f2bf(x1.x + y1.x); o[5] = (short)f2bf(x1.y + y1.y);
    o[6] = (short)f2bf(x1.z + y1.z); o[7] = (short)f2bf(x1.w + y1.w);
    *(short8*)(dst + (size_t)cid * 8) = o;
  }
}

// Flash attention, 64-p block, 4 waves, swapped-S softmax, XCD-swizzled.
// (unchanged from R8; the 21ms dispatch in R8's profile was a rocprof
// artifact -- non-profiled wall time rules out a real 21ms attn.)
__global__ __launch_bounds__(256, 2) void k_attn_mfma(
    const ushort_t* __restrict__ nodes_bf_t,  // [12][1600][256] chunk-swizzled
    const ushort_t* __restrict__ th_t,        // [12][1600][256] plain
    const ushort_t* __restrict__ vf,          // [24][50][16][512] frag-major
    float* __restrict__ agg_t)                // [2][12][1600][256]
{
  __shared__ ushort_t Ej[32 * 256];   // 16 KB
  __shared__ ushort_t Sp[64 * 40];    // 5 KB (rows padded to 40 u16 = 80B)
  __shared__ float Al[64];
  __shared__ float Linv[64];

  const int t = threadIdx.x;
  const int w = t >> 6;               // 0..3
  const int l = t & 63;
  const int quad = l >> 4;
  const int l16 = l & 15;
  // ---- XCD-aware remap (perf-only; mapping assumption xcd = flat%8) ----
  const int F = blockIdx.x + 25 * (blockIdx.y + 12 * blockIdx.z);
  const int wk = (F & 7) * 75 + (F >> 3);        // bijective: 600 = 8*75
  const int p0 = (wk % 25) * 64;
  const int nb = (wk / 25) % 12;
  const int jidx = wk / 300;
  const int n = nb >> 2, b = nb & 3;
  const int e = n * 2 + jidx;
  const int js = jidx + (jidx >= n ? 1 : 0);
  const int eb = e * BB + b;

  const ushort_t* ejb = nodes_bf_t + ((size_t)(js * BB + b) * PP) * CC;  // [q][c-swz]
  const ushort_t* vbase = vf + (size_t)eb * 50 * 8192;

  // th B-frags for this wave's rows p = p0 + 16w + l16 (resident all iters)
  short8 Ath[8];
  {
    const ushort_t* arow = th_t + ((size_t)nb * PP + p0 + 16 * w + l16) * CC + quad * 8;
#pragma unroll
    for (int ks = 0; ks < 8; ++ks) Ath[ks] = *(const short8*)(arow + ks * 32);
  }

  float M = -3.0e38f, Lr = 0.f;       // per-lane: this lane's p-row state
  f32x4 O[4][4];
#pragma unroll
  for (int mt = 0; mt < 4; ++mt)
#pragma unroll
    for (int nt = 0; nt < 4; ++nt)
#pragma unroll
      for (int r = 0; r < 4; ++r) O[mt][nt][r] = 0.f;

  // prologue: stage q-tile 0 (16 chunks of 1KB, wave w does 4)
#pragma unroll
  for (int i = 0; i < 4; ++i)
    async_ld16(ejb + (4 * w + i) * 512 + l * 8, &Ej[(4 * w + i) * 512]);

  for (int T = 0; T < 50; ++T) {
    __syncthreads();   // A: Ej[T] landed (barrier drains vmcnt); Sp/Al free
    // V frags for this iter (coalesced 1KB each); vmcnt-covered by S+softmax
    short8 Bv[4];
    {
      const ushort_t* vt = vbase + (size_t)T * 8192;
#pragma unroll
      for (int nt = 0; nt < 4; ++nt)
        Bv[nt] = *(const short8*)(vt + (4 * w + nt) * 512 + l * 8);
    }
    // ---- swapped S-GEMM: S^T[q][p], rows q = quad*4+r (+16), cols p = l16 ----
    f32x4 S0, S1;
#pragma unroll
    for (int r = 0; r < 4; ++r) { S0[r] = 0.f; S1[r] = 0.f; }
#pragma unroll
    for (int ks = 0; ks < 8; ++ks) {
      int ch0 = (((ks * 4 + quad) ^ (l16 & 7)) << 3);
      short8 A0 = *(const short8*)(Ej + l16 * CC + ch0);
      short8 A1 = *(const short8*)(Ej + (16 + l16) * CC + ch0);
      S0 = __builtin_amdgcn_mfma_f32_16x16x32_bf16(A0, Ath[ks], S0, 0, 0, 0);
      S1 = __builtin_amdgcn_mfma_f32_16x16x32_bf16(A1, Ath[ks], S1, 0, 0, 0);
    }
    // ---- softmax: 8 in-lane q-values for p = p0+16w+l16; reduce across quads ----
    float m = fmaxf(fmaxf(fmaxf(S0[0], S0[1]), fmaxf(S0[2], S0[3])),
                    fmaxf(fmaxf(S1[0], S1[1]), fmaxf(S1[2], S1[3])));
    m = fmaxf(m, __shfl_xor(m, 16));
    m = fmaxf(m, __shfl_xor(m, 32));
    float Mn = fmaxf(M, m);
    float al = __expf(M - Mn);
    float e0 = __expf(S0[0] - Mn), e1 = __expf(S0[1] - Mn);
    float e2 = __expf(S0[2] - Mn), e3 = __expf(S0[3] - Mn);
    float e4 = __expf(S1[0] - Mn), e5 = __expf(S1[1] - Mn);
    float e6 = __expf(S1[2] - Mn), e7 = __expf(S1[3] - Mn);
    float s = ((e0 + e1) + (e2 + e3)) + ((e4 + e5) + (e6 + e7));
    s += __shfl_xor(s, 16);
    s += __shfl_xor(s, 32);
    Lr = Lr * al + s;
    M = Mn;
    {
      uint2 u;
      u.x = (uint_t)f2bf(e0) | ((uint_t)f2bf(e1) << 16);
      u.y = (uint_t)f2bf(e2) | ((uint_t)f2bf(e3) << 16);
      *(uint2*)&Sp[(16 * w + l16) * 40 + quad * 4] = u;
      uint2 v;
      v.x = (uint_t)f2bf(e4) | ((uint_t)f2bf(e5) << 16);
      v.y = (uint_t)f2bf(e6) | ((uint_t)f2bf(e7) << 16);
      *(uint2*)&Sp[(16 * w + l16) * 40 + 16 + quad * 4] = v;
      if (quad == 0) Al[16 * w + l16] = al;
    }
    __syncthreads();   // B: Sp/Al visible; all waves done reading Ej
    // restage Ej for T+1 (nobody reads Ej until next A, which drains vmcnt)
    if (T < 49) {
#pragma unroll
      for (int i = 0; i < 4; ++i)
        async_ld16(ejb + (size_t)(T + 1) * 8192 + (4 * w + i) * 512 + l * 8,
                   &Ej[(4 * w + i) * 512]);
    }
    // ---- rescale O (alpha of row 16mt+quad*4+r via Al broadcast reads) ----
#pragma unroll
    for (int mt = 0; mt < 4; ++mt) {
      f32x4 a4 = *(const f32x4*)&Al[16 * mt + quad * 4];
#pragma unroll
      for (int nt = 0; nt < 4; ++nt)
#pragma unroll
        for (int r = 0; r < 4; ++r) O[mt][nt][r] *= a4[r];
    }
    // ---- PV: O[p=16mt+quad*4+r][c=64w+16nt+l16] ----
#pragma unroll
    for (int mt = 0; mt < 4; ++mt) {
      short8 Ap = *(const short8*)&Sp[(16 * mt + l16) * 40 + quad * 8];
#pragma unroll
      for (int nt = 0; nt < 4; ++nt)
        O[mt][nt] = __builtin_amdgcn_mfma_f32_16x16x32_bf16(Ap, Bv[nt], O[mt][nt], 0, 0, 0);
    }
  }
  // ---- publish 1/L, then epilogue ----
  __syncthreads();
  if (quad == 0) Linv[16 * w + l16] = 1.f / Lr;
  __syncthreads();
  float* ao = agg_t + (((size_t)jidx * NBB + nb) * PP + p0) * CC;
#pragma unroll
  for (int mt = 0; mt < 4; ++mt) {
    f32x4 li = *(const f32x4*)&Linv[16 * mt + quad * 4];
#pragma unroll
    for (int r = 0; r < 4; ++r) {
      float* dst = ao + (size_t)(16 * mt + quad * 4 + r) * CC + 64 * w + l16;
#pragma unroll
      for (int nt = 0; nt < 4; ++nt) dst[16 * nt] = O[mt][nt][r] * li[r];
    }
  }
}

// ---- conv prep ----

// reorder conv weights [M][512][3][3] fp32 -> [M][9][512] bf16
__global__ void k_wrep(const float* __restrict__ w, ushort_t* __restrict__ wr) {
  int i = blockIdx.x * 256 + threadIdx.x;   // M*9*512
  int ci = i & 511;
  int rest = i >> 9;                        // co*9 + tap
  int tp = rest % 9, co = rest / 9;
  wr[i] = f2bf(w[((size_t)co * 512 + ci) * 9 + tp]);
}

__global__ void k_pad_zero(ushort_t* __restrict__ xpad) {
  int i = blockIdx.x * 256 + threadIdx.x;   // 12*1764*512
  xpad[i] = 0;
}

// interior rows, ch 0..255 <- agg_t[0]+agg_t[1]  (both already [px][c])
__global__ void k_pad_agg(const float* __restrict__ agg_t, ushort_t* __restrict__ xpad) {
  int i = blockIdx.x * 256 + threadIdx.x;   // 12*1600*256
  int c = i & 255;
  int rest = i >> 8;
  int px = rest % PP, nb = rest / PP;
  int y = px / 40, x = px - y * 40;
  size_t src = ((size_t)nb * PP + px) * CC + c;
  float v = agg_t[src] + agg_t[(size_t)NBB * PP * CC + src];
  xpad[((size_t)nb * PAD + (y + 1) * 42 + (x + 1)) * C2 + c] = f2bf(v);
}

// interior rows, ch 256..511 <- transpose of srcA [nb][256][1600]
// MODE 0: val = h[c][px];  MODE 1: val = h[c][px] * r[c][px]
template <int MODE>
__global__ void k_pad_tr(const float* __restrict__ srcA, const float* __restrict__ srcB,
                         ushort_t* __restrict__ xpad) {
  __shared__ float tile[32][33];
  int nb = blockIdx.z;
  int c0 = blockIdx.y * 32;
  int pp0 = blockIdx.x * 32;
  int tx = threadIdx.x & 31, ty = threadIdx.x >> 5;
#pragma unroll
  for (int i = 0; i < 4; ++i) {
    int c = c0 + ty + 8 * i;
    float v = srcA[((size_t)nb * CC + c) * PP + pp0 + tx];
    if (MODE == 1) v *= srcB[((size_t)nb * C2 + c) * PP + pp0 + tx];  // r-gate
    tile[ty + 8 * i][tx] = v;
  }
  __syncthreads();
#pragma unroll
  for (int i = 0; i < 4; ++i) {
    int px = pp0 + ty + 8 * i;
    int y = px / 40, x = px - y * 40;
    xpad[((size_t)nb * PAD + (y + 1) * 42 + (x + 1)) * C2 + CC + c0 + tx] =
        f2bf(tile[tx][ty + 8 * i]);
  }
}

// Implicit-GEMM conv3x3, M=co, N=px(1600), K=9 taps x 512 ci.
// Block: 128co x 128px, 4 waves (2x2), each 64x64 (4x4 16x16x32 frags).
//
// R8 post-mortem: XCD swizzle alone cut FETCH only 5% (371->351 MB). The real
// culprit is LOOP ORDER: taps outer meant the same xpad halo region (~18 KB at
// one c-chunk) was re-read by the 9 taps at a reuse distance of 16 iterations
// x ~1 MB/iter of XCD-wide L2 traffic = 16 MB >> 4 MB L2 -> every tap re-read
// (719 MB of 1.44 GB staging) missed to HBM at ~900cy, while per-iter compute
// covers only ~400cy -- which is also why R7's 1-deep double-buffer was
// neutral. R9: it = c_chunk*9 + tap (taps INNERMOST). Reuse distance -> 1
// iteration, footprint 18 KB -> tap re-reads are L1/L2 hits; with the B
// stream no longer thrashing L2, the XCD-pinned weight panel (1.18 MB) stays
// resident across its 78 sharing blocks. Accumulation-order-only change.
//
// ACT 0: out = sigmoid(acc+bias) -> gates [nb][512][1600]
// ACT 1: v = tanh(acc+bias); z = zsrc[256+co]; out(nodes) = (1-z)h + z*v
template <int ACT>
__global__ __launch_bounds__(256) void k_conv_mfma(
    const ushort_t* __restrict__ xpad,   // [12][1764][512]
    const ushort_t* __restrict__ wr,     // [M][9*512]
    const float* __restrict__ bias,      // [M]
    const float* __restrict__ zsrc,      // gates (ACT1)
    float* __restrict__ out)
{
  __shared__ ushort_t Asm[2][128 * 32];
  __shared__ ushort_t Bsm[2][128 * 32];
  const int t = threadIdx.x;
  const int w = t >> 6, l = t & 63, quad = l >> 4, l16 = l & 15;
  // ---- XCD-aware remap (perf-only) ----
  const int gy = gridDim.y;                       // 4 (gates) or 2 (cand)
  const int F = blockIdx.x + 13 * (blockIdx.y + gy * blockIdx.z);
  const int cpx = (13 * gy * 12) >> 3;            // 78 or 39
  const int wk = (F & 7) * cpx + (F >> 3);        // bijective: nwg%8==0
  const int xw = wk % 13;
  const int rest = wk / 13;
  const int nb = rest % 12;
  const int m0 = (rest / 12) * 128;
  const int px0 = xw * 128;
  const int wm = (w >> 1) * 64, wn = (w & 1) * 64;

  // --- staging source setup (lane l covers rows 32w + l/4 and +16) ---
  const int lr = l >> 2;
  const int swf = (lr ^ (lr >> 2)) & 3;          // fill-side XOR swizzle
  const int lk = ((l & 3) ^ swf) * 8;            // k-part (shorts)
  const ushort_t* wsrc = wr + (size_t)(m0 + 32 * w + lr) * 4608 + lk;
  int pxa = px0 + 32 * w + lr;      if (pxa > 1599) pxa = 1599;
  int pxb = pxa + 16;               if (pxb > 1599) pxb = 1599;
  {
    int d = px0 + 32 * w + 16 + lr; if (d <= 1599) pxb = d;
  }
  const int ya = pxa / 40, xa = pxa - ya * 40;
  const int yb = pxb / 40, xb = pxb - yb * 40;
  const ushort_t* bsrc_a = xpad + ((size_t)nb * PAD + ya * 42 + xa) * C2 + lk;
  const ushort_t* bsrc_b = xpad + ((size_t)nb * PAD + yb * 42 + xb) * C2 + lk;

  // --- frag-read swizzle (row&15 == l16 on both A and B) ---
  const int swr = (l16 ^ (l16 >> 2)) & 3;
  const int fk = ((quad ^ swr) * 8);

  f32x4 acc[4][4];
#pragma unroll
  for (int mt = 0; mt < 4; ++mt)
#pragma unroll
    for (int nt = 0; nt < 4; ++nt)
#pragma unroll
      for (int r = 0; r < 4; ++r) acc[mt][nt][r] = 0.f;

  // R9 loop order: it = c_chunk*9 + tap  (taps INNERMOST for L1/L2 reuse).
  // LDS dst is wave-uniform base; HW adds lane*16B.
  auto stage = [&](int buf, int it) {
    int ci = it / 9;                // c-chunk 0..15
    int tap = it - ci * 9;          // tap 0..8
    int cc = ci << 5;               // shorts
    int ky = tap / 3, kx = tap - ky * 3;
    int boff = (ky * 42 + kx) * C2 + cc;
    const ushort_t* wtap = wsrc + tap * 512 + cc;
    async_ld16(wtap, &Asm[buf][w * 1024]);
    async_ld16(wtap + 16 * 4608, &Asm[buf][w * 1024 + 512]);
    async_ld16(bsrc_a + boff, &Bsm[buf][w * 1024]);
    async_ld16(bsrc_b + boff, &Bsm[buf][w * 1024 + 512]);
  };

  stage(0, 0);
  int cur = 0;
#pragma unroll 1
  for (int it = 0; it < 144; ++it) {
    __syncthreads();   // drains vmcnt -> buf[cur] landed; all waves done with buf[cur^1]
    if (it + 1 < 144) stage(cur ^ 1, it + 1);
    short8 Af[4], Bf[4];
#pragma unroll
    for (int mt = 0; mt < 4; ++mt)
      Af[mt] = *(const short8*)(&Asm[cur][0] + (wm + mt * 16 + l16) * 32 + fk);
#pragma unroll
    for (int nt = 0; nt < 4; ++nt)
      Bf[nt] = *(const short8*)(&Bsm[cur][0] + (wn + nt * 16 + l16) * 32 + fk);
#pragma unroll
    for (int mt = 0; mt < 4; ++mt)
#pragma unroll
      for (int nt = 0; nt < 4; ++nt)
        acc[mt][nt] = __builtin_amdgcn_mfma_f32_16x16x32_bf16(Af[mt], Bf[nt], acc[mt][nt], 0, 0, 0);
    cur ^= 1;
  }

  // --- epilogue ---
#pragma unroll
  for (int mt = 0; mt < 4; ++mt) {
#pragma unroll
    for (int r = 0; r < 4; ++r) {
      int co = m0 + wm + mt * 16 + quad * 4 + r;
      float bv = bias[co];
#pragma unroll
      for (int nt = 0; nt < 4; ++nt) {
        int px = px0 + wn + nt * 16 + l16;
        if (px >= PP) continue;
        float v = acc[mt][nt][r] + bv;
        if (ACT == 0) {
          out[((size_t)nb * C2 + co) * PP + px] = 1.f / (1.f + __expf(-v));
        } else {
          v = tanhf(v);
          float z = zsrc[((size_t)nb * C2 + CC + co) * PP + px];
          float* hp = out + ((size_t)nb * CC + co) * PP + px;
          float h = *hp;
          *hp = (1.f - z) * h + z * v;
        }
      }
    }
  }
}

extern "C" void kernel_launch(void* const* d_in, const int* in_sizes, int n_in,
                              void* d_out, int out_size, void* d_ws, size_t ws_size,
                              hipStream_t stream) {
  const float* nodes_in = (const float*)d_in[0];
  const float* tw = (const float*)d_in[1];
  const float* tb = (const float*)d_in[2];
  const float* gw = (const float*)d_in[3];
  const float* gb = (const float*)d_in[4];
  const float* cw = (const float*)d_in[5];
  const float* cb = (const float*)d_in[6];

  float* nodes = (float*)d_out;                      // fp32 state [12][256][1600]
  char* ws = (char*)d_ws;
  // ---- layout (ws >= 98.3 MB) ----
  // attn phase: R0 nodes_bf_t 9.83 | R1 th_t 9.83 | R2 vf 19.66 | R3 agg_t 39.32
  // conv phase: R1+R2 xh_pad 21.68 | R3 gates 39.32
  // persistent:  78.64.. w_g_r 4.72 | 83.36.. w_c_r 2.36   (pass-invariant)
  ushort_t* nodes_bf_t = (ushort_t*)ws;
  ushort_t* th_t  = (ushort_t*)(ws + 9830400);
  ushort_t* vf    = (ushort_t*)(ws + 19660800);
  float*    agg_t = (float*)(ws + 39321600);
  ushort_t* xh_pad = (ushort_t*)(ws + 9830400);      // 12*1764*512*2 = 21,676,032
  float*    gates = (float*)(ws + 39321600);
  ushort_t* w_g_r = (ushort_t*)(ws + 78643200);      // 4,718,592 B
  ushort_t* w_c_r = (ushort_t*)(ws + 83361792);      // 2,359,296 B (ends 85.7 MB)

  k_copy<<<NODESZ / 256, 256, 0, stream>>>(nodes_in, nodes);
  k_wrep<<<(C2 * 9 * C2) / 256, 256, 0, stream>>>(gw, w_g_r);
  k_wrep<<<(CC * 9 * C2) / 256, 256, 0, stream>>>(cw, w_c_r);
  for (int pass = 0; pass < 2; ++pass) {
    // ---- attention ----
    k_theta<<<dim3(5, NBB * (CC / TO)), 320, 0, stream>>>(nodes, tw, tb, th_t);
    k_to_bf_t<<<dim3(50, 8, NBB), 256, 0, stream>>>(nodes, nodes_bf_t);
    k_prep_vf<<<dim3(50, 24), 256, 0, stream>>>(nodes, vf);
    k_attn_mfma<<<dim3(25, NBB, 2), 256, 0, stream>>>(nodes_bf_t, th_t, vf, agg_t);
    // ---- conv prep (attn scratch now dead) ----
    k_pad_zero<<<(NBB * PAD * C2) / 256, 256, 0, stream>>>(xh_pad);
    k_pad_agg<<<(NBB * PP * CC) / 256, 256, 0, stream>>>(agg_t, xh_pad);
    k_pad_tr<0><<<dim3(50, 8, NBB), 256, 0, stream>>>(nodes, nullptr, xh_pad);
    // ---- gates conv ----
    k_conv_mfma<0><<<dim3(13, 4, NBB), 256, 0, stream>>>(xh_pad, w_g_r, gb, nullptr, gates);
    // ---- r*h into xh_pad high channels ----
    k_pad_tr<1><<<dim3(50, 8, NBB), 256, 0, stream>>>(nodes, gates, xh_pad);
    // ---- cand conv + fused GRU update ----
    k_conv_mfma<1><<<dim3(13, 2, NBB), 256, 0, stream>>>(xh_pad, w_c_r, cb, gates, nodes);
  }
}

// Round 10
// 1057.096 us; speedup vs baseline: 1.0514x; 1.0206x over previous
//
#include <hip/hip_runtime.h>
#include <hip/hip_bf16.h>
#include <math.h>

#define NN 3
#define BB 4
#define CC 256
#define C2 512
#define HH 40
#define WW 40
#define PP 1600
#define NBB 12                  // NN*BB
#define NODESZ (NBB*CC*PP)      // 4,915,200
#define TO 16                   // theta: output channels per block
#define PAD 1764                // 42*42 padded pixels

typedef short short8 __attribute__((ext_vector_type(8)));
typedef float f32x4 __attribute__((ext_vector_type(4)));
typedef unsigned short ushort_t;
typedef unsigned int uint_t;

__device__ __forceinline__ ushort_t f2bf(float x) {
  union { float f; uint_t u; } v; v.f = x;
  uint_t r = v.u + 0x7fff + ((v.u >> 16) & 1);
  return (ushort_t)(r >> 16);
}

__device__ __forceinline__ void async_ld16(const ushort_t* g, ushort_t* l) {
  __builtin_amdgcn_global_load_lds(
      (const __attribute__((address_space(1))) uint_t*)g,
      (__attribute__((address_space(3))) uint_t*)l, 16, 0, 0);
}

__global__ void k_copy(const float* __restrict__ in, float* __restrict__ out) {
  int i = blockIdx.x * 256 + threadIdx.x;
  out[i] = in[i];
}

// th_t[nb][p][c] (bf16) = tb[o] + sum_c tw[o,c] * nodes[nb,c,p]
__global__ void k_theta(const float* __restrict__ nodes, const float* __restrict__ tw,
                        const float* __restrict__ tb, ushort_t* __restrict__ th_t) {
  __shared__ float w[TO * CC];
  int t = threadIdx.x;
  int nb = blockIdx.y / (CC / TO);
  int o0 = (blockIdx.y % (CC / TO)) * TO;
  for (int i = t; i < TO * CC; i += 320) w[i] = tw[(o0 + (i >> 8)) * CC + (i & 255)];
  __syncthreads();
  int p = blockIdx.x * 320 + t;
  const float* src = nodes + nb * CC * PP + p;
  float acc[TO];
#pragma unroll
  for (int o = 0; o < TO; ++o) acc[o] = tb[o0 + o];
  for (int c = 0; c < CC; c += 4) {
    float v0 = src[c * PP], v1 = src[(c + 1) * PP], v2 = src[(c + 2) * PP], v3 = src[(c + 3) * PP];
#pragma unroll
    for (int o = 0; o < TO; ++o) {
      const float4 ww = *(const float4*)(w + o * CC + c);
      acc[o] += ww.x * v0 + ww.y * v1 + ww.z * v2 + ww.w * v3;
    }
  }
  size_t base = ((size_t)nb * PP + p) * CC + o0;
#pragma unroll
  for (int o = 0; o < TO; o += 2) {
    uint_t lo = f2bf(acc[o]), hi = f2bf(acc[o + 1]);
    *(uint_t*)&th_t[base + o] = lo | (hi << 16);
  }
}

// nodes [12][256][1600] fp32 -> nodes_bf_t [12][1600][256] bf16 (transpose),
// with 16B-chunk XOR swizzle within each row: c' = c ^ ((q&7)<<3).
// (Consumed only by k_attn_mfma, which un-XORs on its LDS frag reads.)
__global__ void k_to_bf_t(const float* __restrict__ src, ushort_t* __restrict__ dst) {
  __shared__ float tile[32][33];
  int nb = blockIdx.z;
  int c0 = blockIdx.y * 32;
  int pp0 = blockIdx.x * 32;
  int tx = threadIdx.x & 31, ty = threadIdx.x >> 5;
#pragma unroll
  for (int i = 0; i < 4; ++i)
    tile[ty + 8 * i][tx] = src[((size_t)nb * CC + c0 + ty + 8 * i) * PP + pp0 + tx];
  __syncthreads();
#pragma unroll
  for (int i = 0; i < 4; ++i) {
    int q = pp0 + ty + 8 * i;
    int c = c0 + tx;
    int cs = c ^ ((q & 7) << 3);
    dst[((size_t)nb * PP + q) * CC + cs] = f2bf(tile[tx][ty + 8 * i]);
  }
}

// vf frag-major bf16: vf[eb][T][nt][lane(quad,l16)][j]
//   = nodes[recv][c][p] + nodes[send][c][p],  c = 16nt + l16, p = 32T + quad*8 + j
// Each (T,nt) PV B-fragment = contiguous 1KB, one coalesced load in attn.
__global__ void k_prep_vf(const float* __restrict__ nodes, ushort_t* __restrict__ vf) {
  int T = blockIdx.x;                   // 0..49
  int eb = blockIdx.y;                  // 0..23
  int e = eb >> 2, b = eb & 3;
  int n = e >> 1, jidx = e & 1;
  int js = jidx + (jidx >= n ? 1 : 0);
  const float* s0 = nodes + (size_t)(n * BB + b) * CC * PP;
  const float* s1 = nodes + (size_t)(js * BB + b) * CC * PP;
  ushort_t* dst = vf + ((size_t)eb * 50 + T) * 8192;
  int t = threadIdx.x;
#pragma unroll
  for (int k = 0; k < 4; ++k) {
    int cid = t + 256 * k;              // 0..1023 (16 nt x 64 lanes)
    int nt = cid >> 6, l = cid & 63;
    int quad = l >> 4, l16 = l & 15;
    int c = 16 * nt + l16;
    int p = 32 * T + quad * 8;
    const float4* a0 = (const float4*)(s0 + (size_t)c * PP + p);
    const float4* a1 = (const float4*)(s1 + (size_t)c * PP + p);
    float4 x0 = a0[0], x1 = a0[1];
    float4 y0 = a1[0], y1 = a1[1];
    short8 o;
    o[0] = (short)f2bf(x0.x + y0.x); o[1] = (short)f2bf(x0.y + y0.y);
    o[2] = (short)f2bf(x0.z + y0.z); o[3] = (short)f2bf(x0.w + y0.w);
    o[4] = (short)f2bf(x1.x + y1.x); o[5] = (short)f2bf(x1.y + y1.y);
    o[6] = (short)f2bf(x1.z + y1.z); o[7] = (short)f2bf(x1.w + y1.w);
    *(short8*)(dst + (size_t)cid * 8) = o;
  }
}

// Flash attention, 64-p block, 4 waves, swapped-S softmax, XCD-swizzled.
// (unchanged from R8/R9; out of the profile top-5.)
__global__ __launch_bounds__(256, 2) void k_attn_mfma(
    const ushort_t* __restrict__ nodes_bf_t,  // [12][1600][256] chunk-swizzled
    const ushort_t* __restrict__ th_t,        // [12][1600][256] plain
    const ushort_t* __restrict__ vf,          // [24][50][16][512] frag-major
    float* __restrict__ agg_t)                // [2][12][1600][256]
{
  __shared__ ushort_t Ej[32 * 256];   // 16 KB
  __shared__ ushort_t Sp[64 * 40];    // 5 KB (rows padded to 40 u16 = 80B)
  __shared__ float Al[64];
  __shared__ float Linv[64];

  const int t = threadIdx.x;
  const int w = t >> 6;               // 0..3
  const int l = t & 63;
  const int quad = l >> 4;
  const int l16 = l & 15;
  // ---- XCD-aware remap (perf-only; mapping assumption xcd = flat%8) ----
  const int F = blockIdx.x + 25 * (blockIdx.y + 12 * blockIdx.z);
  const int wk = (F & 7) * 75 + (F >> 3);        // bijective: 600 = 8*75
  const int p0 = (wk % 25) * 64;
  const int nb = (wk / 25) % 12;
  const int jidx = wk / 300;
  const int n = nb >> 2, b = nb & 3;
  const int e = n * 2 + jidx;
  const int js = jidx + (jidx >= n ? 1 : 0);
  const int eb = e * BB + b;

  const ushort_t* ejb = nodes_bf_t + ((size_t)(js * BB + b) * PP) * CC;  // [q][c-swz]
  const ushort_t* vbase = vf + (size_t)eb * 50 * 8192;

  // th B-frags for this wave's rows p = p0 + 16w + l16 (resident all iters)
  short8 Ath[8];
  {
    const ushort_t* arow = th_t + ((size_t)nb * PP + p0 + 16 * w + l16) * CC + quad * 8;
#pragma unroll
    for (int ks = 0; ks < 8; ++ks) Ath[ks] = *(const short8*)(arow + ks * 32);
  }

  float M = -3.0e38f, Lr = 0.f;       // per-lane: this lane's p-row state
  f32x4 O[4][4];
#pragma unroll
  for (int mt = 0; mt < 4; ++mt)
#pragma unroll
    for (int nt = 0; nt < 4; ++nt)
#pragma unroll
      for (int r = 0; r < 4; ++r) O[mt][nt][r] = 0.f;

  // prologue: stage q-tile 0 (16 chunks of 1KB, wave w does 4)
#pragma unroll
  for (int i = 0; i < 4; ++i)
    async_ld16(ejb + (4 * w + i) * 512 + l * 8, &Ej[(4 * w + i) * 512]);

  for (int T = 0; T < 50; ++T) {
    __syncthreads();   // A: Ej[T] landed (barrier drains vmcnt); Sp/Al free
    // V frags for this iter (coalesced 1KB each); vmcnt-covered by S+softmax
    short8 Bv[4];
    {
      const ushort_t* vt = vbase + (size_t)T * 8192;
#pragma unroll
      for (int nt = 0; nt < 4; ++nt)
        Bv[nt] = *(const short8*)(vt + (4 * w + nt) * 512 + l * 8);
    }
    // ---- swapped S-GEMM: S^T[q][p], rows q = quad*4+r (+16), cols p = l16 ----
    f32x4 S0, S1;
#pragma unroll
    for (int r = 0; r < 4; ++r) { S0[r] = 0.f; S1[r] = 0.f; }
#pragma unroll
    for (int ks = 0; ks < 8; ++ks) {
      int ch0 = (((ks * 4 + quad) ^ (l16 & 7)) << 3);
      short8 A0 = *(const short8*)(Ej + l16 * CC + ch0);
      short8 A1 = *(const short8*)(Ej + (16 + l16) * CC + ch0);
      S0 = __builtin_amdgcn_mfma_f32_16x16x32_bf16(A0, Ath[ks], S0, 0, 0, 0);
      S1 = __builtin_amdgcn_mfma_f32_16x16x32_bf16(A1, Ath[ks], S1, 0, 0, 0);
    }
    // ---- softmax: 8 in-lane q-values for p = p0+16w+l16; reduce across quads ----
    float m = fmaxf(fmaxf(fmaxf(S0[0], S0[1]), fmaxf(S0[2], S0[3])),
                    fmaxf(fmaxf(S1[0], S1[1]), fmaxf(S1[2], S1[3])));
    m = fmaxf(m, __shfl_xor(m, 16));
    m = fmaxf(m, __shfl_xor(m, 32));
    float Mn = fmaxf(M, m);
    float al = __expf(M - Mn);
    float e0 = __expf(S0[0] - Mn), e1 = __expf(S0[1] - Mn);
    float e2 = __expf(S0[2] - Mn), e3 = __expf(S0[3] - Mn);
    float e4 = __expf(S1[0] - Mn), e5 = __expf(S1[1] - Mn);
    float e6 = __expf(S1[2] - Mn), e7 = __expf(S1[3] - Mn);
    float s = ((e0 + e1) + (e2 + e3)) + ((e4 + e5) + (e6 + e7));
    s += __shfl_xor(s, 16);
    s += __shfl_xor(s, 32);
    Lr = Lr * al + s;
    M = Mn;
    {
      uint2 u;
      u.x = (uint_t)f2bf(e0) | ((uint_t)f2bf(e1) << 16);
      u.y = (uint_t)f2bf(e2) | ((uint_t)f2bf(e3) << 16);
      *(uint2*)&Sp[(16 * w + l16) * 40 + quad * 4] = u;
      uint2 v;
      v.x = (uint_t)f2bf(e4) | ((uint_t)f2bf(e5) << 16);
      v.y = (uint_t)f2bf(e6) | ((uint_t)f2bf(e7) << 16);
      *(uint2*)&Sp[(16 * w + l16) * 40 + 16 + quad * 4] = v;
      if (quad == 0) Al[16 * w + l16] = al;
    }
    __syncthreads();   // B: Sp/Al visible; all waves done reading Ej
    // restage Ej for T+1 (nobody reads Ej until next A, which drains vmcnt)
    if (T < 49) {
#pragma unroll
      for (int i = 0; i < 4; ++i)
        async_ld16(ejb + (size_t)(T + 1) * 8192 + (4 * w + i) * 512 + l * 8,
                   &Ej[(4 * w + i) * 512]);
    }
    // ---- rescale O (alpha of row 16mt+quad*4+r via Al broadcast reads) ----
#pragma unroll
    for (int mt = 0; mt < 4; ++mt) {
      f32x4 a4 = *(const f32x4*)&Al[16 * mt + quad * 4];
#pragma unroll
      for (int nt = 0; nt < 4; ++nt)
#pragma unroll
        for (int r = 0; r < 4; ++r) O[mt][nt][r] *= a4[r];
    }
    // ---- PV: O[p=16mt+quad*4+r][c=64w+16nt+l16] ----
#pragma unroll
    for (int mt = 0; mt < 4; ++mt) {
      short8 Ap = *(const short8*)&Sp[(16 * mt + l16) * 40 + quad * 8];
#pragma unroll
      for (int nt = 0; nt < 4; ++nt)
        O[mt][nt] = __builtin_amdgcn_mfma_f32_16x16x32_bf16(Ap, Bv[nt], O[mt][nt], 0, 0, 0);
    }
  }
  // ---- publish 1/L, then epilogue ----
  __syncthreads();
  if (quad == 0) Linv[16 * w + l16] = 1.f / Lr;
  __syncthreads();
  float* ao = agg_t + (((size_t)jidx * NBB + nb) * PP + p0) * CC;
#pragma unroll
  for (int mt = 0; mt < 4; ++mt) {
    f32x4 li = *(const f32x4*)&Linv[16 * mt + quad * 4];
#pragma unroll
    for (int r = 0; r < 4; ++r) {
      float* dst = ao + (size_t)(16 * mt + quad * 4 + r) * CC + 64 * w + l16;
#pragma unroll
      for (int nt = 0; nt < 4; ++nt) dst[16 * nt] = O[mt][nt][r] * li[r];
    }
  }
}

// ---- conv prep ----

// reorder conv weights [M][512][3][3] fp32 -> [M][9][512] bf16
__global__ void k_wrep(const float* __restrict__ w, ushort_t* __restrict__ wr) {
  int i = blockIdx.x * 256 + threadIdx.x;   // M*9*512
  int ci = i & 511;
  int rest = i >> 9;                        // co*9 + tap
  int tp = rest % 9, co = rest / 9;
  wr[i] = f2bf(w[((size_t)co * 512 + ci) * 9 + tp]);
}

__global__ void k_pad_zero(ushort_t* __restrict__ xpad) {
  int i = blockIdx.x * 256 + threadIdx.x;   // 12*1764*512
  xpad[i] = 0;
}

// interior rows, ch 0..255 <- agg_t[0]+agg_t[1]  (both already [px][c])
__global__ void k_pad_agg(const float* __restrict__ agg_t, ushort_t* __restrict__ xpad) {
  int i = blockIdx.x * 256 + threadIdx.x;   // 12*1600*256
  int c = i & 255;
  int rest = i >> 8;
  int px = rest % PP, nb = rest / PP;
  int y = px / 40, x = px - y * 40;
  size_t src = ((size_t)nb * PP + px) * CC + c;
  float v = agg_t[src] + agg_t[(size_t)NBB * PP * CC + src];
  xpad[((size_t)nb * PAD + (y + 1) * 42 + (x + 1)) * C2 + c] = f2bf(v);
}

// interior rows, ch 256..511 <- transpose of srcA [nb][256][1600]
// MODE 0: val = h[c][px];  MODE 1: val = h[c][px] * r[c][px]
template <int MODE>
__global__ void k_pad_tr(const float* __restrict__ srcA, const float* __restrict__ srcB,
                         ushort_t* __restrict__ xpad) {
  __shared__ float tile[32][33];
  int nb = blockIdx.z;
  int c0 = blockIdx.y * 32;
  int pp0 = blockIdx.x * 32;
  int tx = threadIdx.x & 31, ty = threadIdx.x >> 5;
#pragma unroll
  for (int i = 0; i < 4; ++i) {
    int c = c0 + ty + 8 * i;
    float v = srcA[((size_t)nb * CC + c) * PP + pp0 + tx];
    if (MODE == 1) v *= srcB[((size_t)nb * C2 + c) * PP + pp0 + tx];  // r-gate
    tile[ty + 8 * i][tx] = v;
  }
  __syncthreads();
#pragma unroll
  for (int i = 0; i < 4; ++i) {
    int px = pp0 + ty + 8 * i;
    int y = px / 40, x = px - y * 40;
    xpad[((size_t)nb * PAD + (y + 1) * 42 + (x + 1)) * C2 + CC + c0 + tx] =
        f2bf(tile[tx][ty + 8 * i]);
  }
}

// Implicit-GEMM conv3x3, M=co, N=px(1600), K=9 taps x 512 ci.
// Block: 128co x 128px, 4 waves (2x2), each 64x64 (4x4 16x16x32 frags).
//
// R9 post-mortem: FETCH collapsed 351->47 MB but dur 151->139 only. Staging
// still moves 16KB x 144 x 624 = 1.44 GB at the L2->LDS level in 139us =
// 10.3 TB/s -- the SAME ~10 TB/s plateau attn hit (R4/R5/R6). The conv is
// staging-path-byte-bound. Half those bytes are B, and B is 9x redundant
// (each tap re-stages the same pixel slab).
// R10: HALO-SLAB REUSE. Per c-chunk (32 ch), stage the contiguous 256-pixel
// xpad slab [slab0, slab0+256) ONCE (16KB, double-buffered); all 9 taps read
// their B-frags from it at row = pb[nt] + ky*42+kx with XOR swizzle
// s = quad ^ ((R^(R>>2))&3) (2-way max = free). A path byte-identical to R9.
// Staging: 16 -> 8 + 16/9 ~= 9.8 KB/iter (0.61x, ~880 MB/dispatch).
// Accumulation order unchanged -> numerics identical to R9. OOB slab rows of
// the last px-block read garbage inside ws (never consumed; epilogue clamps).
//
// ACT 0: out = sigmoid(acc+bias) -> gates [nb][512][1600]
// ACT 1: v = tanh(acc+bias); z = zsrc[256+co]; out(nodes) = (1-z)h + z*v
template <int ACT>
__global__ __launch_bounds__(256) void k_conv_mfma(
    const ushort_t* __restrict__ xpad,   // [12][1764][512]
    const ushort_t* __restrict__ wr,     // [M][9*512]
    const float* __restrict__ bias,      // [M]
    const float* __restrict__ zsrc,      // gates (ACT1)
    float* __restrict__ out)
{
  __shared__ ushort_t Asm[2][128 * 32];   // 2 x 8 KB   (A: 128co x 32ch)
  __shared__ ushort_t Bsl[2][256 * 32];   // 2 x 16 KB  (B slab: 256 px x 32ch)
  const int t = threadIdx.x;
  const int w = t >> 6, l = t & 63, quad = l >> 4, l16 = l & 15;
  // ---- XCD-aware remap (perf-only) ----
  const int gy = gridDim.y;                       // 4 (gates) or 2 (cand)
  const int F = blockIdx.x + 13 * (blockIdx.y + gy * blockIdx.z);
  const int cpx = (13 * gy * 12) >> 3;            // 78 or 39
  const int wk = (F & 7) * cpx + (F >> 3);        // bijective: nwg%8==0
  const int xw = wk % 13;
  const int rest = wk / 13;
  const int nb = rest % 12;
  const int m0 = (rest / 12) * 128;
  const int px0 = xw * 128;
  const int wm = (w >> 1) * 64, wn = (w & 1) * 64;

  // --- A staging source (unchanged from R9): lane l covers rows 32w+lr, +16 ---
  const int lr = l >> 2;
  const int swf = (lr ^ (lr >> 2)) & 3;          // fill-side XOR swizzle
  const int lk = ((l & 3) ^ swf) * 8;            // k-part (shorts)
  const ushort_t* wsrc = wr + (size_t)(m0 + 32 * w + lr) * 4608 + lk;

  // --- B slab staging source: wave w covers slab rows [64w, 64w+64) ---
  // slab0 = base(px0) = px0 + 2*(px0/40); slab row R holds xpad pixel slab0+R.
  // LDS pos chunk (l&3) of row (l>>2) holds logical chunk (l&3)^sigma(R),
  // sigma(R) = (R ^ (R>>2)) & 3  (store side: fetch global chunk (l&3)^sigma).
  const int slab0 = px0 + 2 * (px0 / 40);
  const int sgm = ((l >> 2) ^ (l >> 4)) & 3;
  const ushort_t* bslab_src =
      xpad + ((size_t)nb * PAD + slab0 + 64 * w + (l >> 2)) * C2 + ((l & 3) ^ sgm) * 8;

  // --- per-lane B-frag slab rows: pb[nt] = base(px) - slab0, px = px0+wn+nt*16+l16
  int pb[4];
#pragma unroll
  for (int nt = 0; nt < 4; ++nt) {
    int px = px0 + wn + nt * 16 + l16;
    pb[nt] = px + 2 * (px / 40) - slab0;
  }

  // --- A frag-read swizzle (unchanged) ---
  const int swr = (l16 ^ (l16 >> 2)) & 3;
  const int fk = ((quad ^ swr) * 8);

  f32x4 acc[4][4];
#pragma unroll
  for (int mt = 0; mt < 4; ++mt)
#pragma unroll
    for (int nt = 0; nt < 4; ++nt)
#pragma unroll
      for (int r = 0; r < 4; ++r) acc[mt][nt][r] = 0.f;

  // stageA for flat it = cc*9 + tap (taps innermost, same order as R9)
  auto stageA = [&](int buf, int it) {
    int ci = it / 9;
    int tap = it - ci * 9;
    const ushort_t* s = wsrc + tap * 512 + ci * 32;
    async_ld16(s, &Asm[buf][w * 1024]);
    async_ld16(s + 16 * 4608, &Asm[buf][w * 1024 + 512]);
  };
  // stageB slab for c-chunk cc: 4 asyncs/wave, 16 rows each
  auto stageB = [&](int buf, int cc) {
    const ushort_t* s = bslab_src + cc * 32;
#pragma unroll
    for (int i = 0; i < 4; ++i)
      async_ld16(s + (size_t)i * 16 * C2, &Bsl[buf][w * 2048 + i * 512]);
  };

  stageB(0, 0);
  stageA(0, 0);
  int ab = 0, bb = 0;
#pragma unroll 1
  for (int cc = 0; cc < 16; ++cc) {
#pragma unroll 1
    for (int tap = 0; tap < 9; ++tap) {
      __syncthreads();   // drains vmcnt: Asm[ab] (and slab if just staged) ready
      int nit = cc * 9 + tap + 1;
      if (nit < 144) stageA(ab ^ 1, nit);
      if (tap == 0 && cc + 1 < 16) stageB(bb ^ 1, cc + 1);
      const int ky = tap / 3;
      const int toff = ky * 42 + (tap - 3 * ky);
      short8 Af[4], Bf[4];
#pragma unroll
      for (int mt = 0; mt < 4; ++mt)
        Af[mt] = *(const short8*)(&Asm[ab][0] + (wm + mt * 16 + l16) * 32 + fk);
#pragma unroll
      for (int nt = 0; nt < 4; ++nt) {
        int R = pb[nt] + toff;
        Bf[nt] = *(const short8*)(&Bsl[bb][0] + R * 32 + ((quad ^ ((R ^ (R >> 2)) & 3)) << 3));
      }
#pragma unroll
      for (int mt = 0; mt < 4; ++mt)
#pragma unroll
        for (int nt = 0; nt < 4; ++nt)
          acc[mt][nt] = __builtin_amdgcn_mfma_f32_16x16x32_bf16(Af[mt], Bf[nt], acc[mt][nt], 0, 0, 0);
      ab ^= 1;
    }
    bb ^= 1;
  }

  // --- epilogue ---
#pragma unroll
  for (int mt = 0; mt < 4; ++mt) {
#pragma unroll
    for (int r = 0; r < 4; ++r) {
      int co = m0 + wm + mt * 16 + quad * 4 + r;
      float bv = bias[co];
#pragma unroll
      for (int nt = 0; nt < 4; ++nt) {
        int px = px0 + wn + nt * 16 + l16;
        if (px >= PP) continue;
        float v = acc[mt][nt][r] + bv;
        if (ACT == 0) {
          out[((size_t)nb * C2 + co) * PP + px] = 1.f / (1.f + __expf(-v));
        } else {
          v = tanhf(v);
          float z = zsrc[((size_t)nb * C2 + CC + co) * PP + px];
          float* hp = out + ((size_t)nb * CC + co) * PP + px;
          float h = *hp;
          *hp = (1.f - z) * h + z * v;
        }
      }
    }
  }
}

extern "C" void kernel_launch(void* const* d_in, const int* in_sizes, int n_in,
                              void* d_out, int out_size, void* d_ws, size_t ws_size,
                              hipStream_t stream) {
  const float* nodes_in = (const float*)d_in[0];
  const float* tw = (const float*)d_in[1];
  const float* tb = (const float*)d_in[2];
  const float* gw = (const float*)d_in[3];
  const float* gb = (const float*)d_in[4];
  const float* cw = (const float*)d_in[5];
  const float* cb = (const float*)d_in[6];

  float* nodes = (float*)d_out;                      // fp32 state [12][256][1600]
  char* ws = (char*)d_ws;
  // ---- layout (ws >= 98.3 MB) ----
  // attn phase: R0 nodes_bf_t 9.83 | R1 th_t 9.83 | R2 vf 19.66 | R3 agg_t 39.32
  // conv phase: R1+R2 xh_pad 21.68 | R3 gates 39.32
  // persistent:  78.64.. w_g_r 4.72 | 83.36.. w_c_r 2.36   (pass-invariant)
  ushort_t* nodes_bf_t = (ushort_t*)ws;
  ushort_t* th_t  = (ushort_t*)(ws + 9830400);
  ushort_t* vf    = (ushort_t*)(ws + 19660800);
  float*    agg_t = (float*)(ws + 39321600);
  ushort_t* xh_pad = (ushort_t*)(ws + 9830400);      // 12*1764*512*2 = 21,676,032
  float*    gates = (float*)(ws + 39321600);
  ushort_t* w_g_r = (ushort_t*)(ws + 78643200);      // 4,718,592 B
  ushort_t* w_c_r = (ushort_t*)(ws + 83361792);      // 2,359,296 B (ends 85.7 MB)

  k_copy<<<NODESZ / 256, 256, 0, stream>>>(nodes_in, nodes);
  k_wrep<<<(C2 * 9 * C2) / 256, 256, 0, stream>>>(gw, w_g_r);
  k_wrep<<<(CC * 9 * C2) / 256, 256, 0, stream>>>(cw, w_c_r);
  for (int pass = 0; pass < 2; ++pass) {
    // ---- attention ----
    k_theta<<<dim3(5, NBB * (CC / TO)), 320, 0, stream>>>(nodes, tw, tb, th_t);
    k_to_bf_t<<<dim3(50, 8, NBB), 256, 0, stream>>>(nodes, nodes_bf_t);
    k_prep_vf<<<dim3(50, 24), 256, 0, stream>>>(nodes, vf);
    k_attn_mfma<<<dim3(25, NBB, 2), 256, 0, stream>>>(nodes_bf_t, th_t, vf, agg_t);
    // ---- conv prep (attn scratch now dead) ----
    k_pad_zero<<<(NBB * PAD * C2) / 256, 256, 0, stream>>>(xh_pad);
    k_pad_agg<<<(NBB * PP * CC) / 256, 256, 0, stream>>>(agg_t, xh_pad);
    k_pad_tr<0><<<dim3(50, 8, NBB), 256, 0, stream>>>(nodes, nullptr, xh_pad);
    // ---- gates conv ----
    k_conv_mfma<0><<<dim3(13, 4, NBB), 256, 0, stream>>>(xh_pad, w_g_r, gb, nullptr, gates);
    // ---- r*h into xh_pad high channels ----
    k_pad_tr<1><<<dim3(50, 8, NBB), 256, 0, stream>>>(nodes, gates, xh_pad);
    // ---- cand conv + fused GRU update ----
    k_conv_mfma<1><<<dim3(13, 2, NBB), 256, 0, stream>>>(xh_pad, w_c_r, cb, gates, nodes);
  }
}